// Round 5
// baseline (443.630 us; speedup 1.0000x reference)
//
#include <hip/hip_runtime.h>
#include <stdint.h>

typedef unsigned int u32;
typedef unsigned short u16;
typedef float f32x4 __attribute__((ext_vector_type(4)));
typedef float f32x2 __attribute__((ext_vector_type(2)));
typedef short short8 __attribute__((ext_vector_type(8)));
typedef unsigned short ushort8 __attribute__((ext_vector_type(8)));
typedef unsigned int u32x2 __attribute__((ext_vector_type(2)));
typedef unsigned int u32x4 __attribute__((ext_vector_type(4)));

#define HID  128
#define MT   16        // batch rows per WG
#define NWG  512       // 8192/16, 2 WGs per CU -> co-resident (22KB LDS, <=128 VGPR)
#define NTHR 512       // 8 waves
#define LD   136       // LDS plane stride in u16 (272B rows)

// ---- ws byte offsets ----
#define OFF_PART  0        // 2 x 512 f32 (parity double-buffered)
#define OFF_CNT   4096     // 64 u32
#define OFF_WPACK 8192     // 644 f32: W1(256) b1(128) b2(128) b3(128) b4(2)
#define OFF_W2TH  16384    // 128x128 bf16 [n][k] hi
#define OFF_W2TL  49152
#define OFF_W3TH  81920
#define OFF_W3TL  114688

constexpr float CA21 = (float)(1.0/5.0);
constexpr float CA31 = (float)(3.0/40.0),   CA32 = (float)(9.0/40.0);
constexpr float CA41 = (float)(44.0/45.0),  CA42 = (float)(-56.0/15.0), CA43 = (float)(32.0/9.0);
constexpr float CA51 = (float)(19372.0/6561.0), CA52 = (float)(-25360.0/2187.0);
constexpr float CA53 = (float)(64448.0/6561.0), CA54 = (float)(-212.0/729.0);
constexpr float CA61 = (float)(9017.0/3168.0),  CA62 = (float)(-355.0/33.0);
constexpr float CA63 = (float)(46732.0/5247.0), CA64 = (float)(49.0/176.0), CA65 = (float)(-5103.0/18656.0);
constexpr float CB1 = (float)(35.0/384.0), CB3 = (float)(500.0/1113.0), CB4 = (float)(125.0/192.0);
constexpr float CB5 = (float)(-2187.0/6784.0), CB6 = (float)(11.0/84.0);
constexpr float CE1 = (float)(35.0/384.0 - 5179.0/57600.0);
constexpr float CE3 = (float)(500.0/1113.0 - 7571.0/16695.0);
constexpr float CE4 = (float)(125.0/192.0 - 393.0/640.0);
constexpr float CE5 = (float)(-2187.0/6784.0 + 92097.0/339200.0);
constexpr float CE6 = (float)(11.0/84.0 - 187.0/2100.0);
constexpr float CE7 = (float)(-1.0/40.0);

template<int N> struct IC { static constexpr int v = N; };

__device__ __forceinline__ u16 f2bf(float x) {
  u32 u = __builtin_bit_cast(u32, x);
  u32 r = (u + 0x7FFFu + ((u >> 16) & 1u)) >> 16;
  return (u16)r;
}
__device__ __forceinline__ float bf2f(u16 b) {
  u32 u = ((u32)b) << 16;
  return __builtin_bit_cast(float, u);
}
__device__ __forceinline__ float eluf(float x) {
  return x > 0.f ? x : (__expf(x) - 1.f);
}
// v_cvt_pk_bf16_f32: dst[15:0]=bf16(a), dst[31:16]=bf16(b) (RNE)
__device__ __forceinline__ u32 cvtpk(float a, float b) {
  u32 r; asm("v_cvt_pk_bf16_f32 %0, %1, %2" : "=v"(r) : "v"(a), "v"(b)); return r;
}

// ---------------------------------------------------------------------------
// Prologue
// ---------------------------------------------------------------------------
__global__ void prologue(const float* __restrict__ x0, const float* __restrict__ t,
                         const float* __restrict__ W1, const float* __restrict__ b1,
                         const float* __restrict__ W2, const float* __restrict__ b2,
                         const float* __restrict__ W3, const float* __restrict__ b3,
                         const float* __restrict__ W4, const float* __restrict__ b4,
                         float* __restrict__ ws, float* __restrict__ out)
{
  int gid = blockIdx.x * blockDim.x + threadIdx.x;   // 64*256 = 16384
  out[gid] = x0[gid];
  {
    int k = gid >> 7, j = gid & 127;
    u16* w2th = (u16*)((char*)ws + OFF_W2TH);
    u16* w2tl = (u16*)((char*)ws + OFF_W2TL);
    u16* w3th = (u16*)((char*)ws + OFF_W3TH);
    u16* w3tl = (u16*)((char*)ws + OFF_W3TL);
    float w = W2[gid];
    u16 hb = f2bf(w);
    w2th[j*HID + k] = hb;
    w2tl[j*HID + k] = f2bf(w - bf2f(hb));
    w = W3[gid];
    hb = f2bf(w);
    w3th[j*HID + k] = hb;
    w3tl[j*HID + k] = f2bf(w - bf2f(hb));
  }
  float* wp = ws + OFF_WPACK/4;
  if (gid < 256) wp[gid] = W1[gid];
  if (gid < 128) {
    wp[256 + gid] = b1[gid];
    wp[384 + gid] = b2[gid];
    wp[512 + gid] = b3[gid];
  }
  if (gid < 2)  wp[640 + gid] = b4[gid];
  if (gid < 64) ((u32*)((char*)ws + OFF_CNT))[gid] = 0u;
}

// ---------------------------------------------------------------------------
// Persistent solver: 512 WGs x 512 threads, 2 WGs per CU.
// ---------------------------------------------------------------------------
__global__ __launch_bounds__(NTHR, 4)
void solver(const float* __restrict__ x0, const float* __restrict__ t_arr,
            const float* __restrict__ W4g, float* __restrict__ ws,
            float* __restrict__ out)
{
  const int tid  = threadIdx.x;
  const int wg   = blockIdx.x;
  const int lane = tid & 63;
  const int wv   = tid >> 6;
  const int nl   = lane & 15;      // MFMA fragment index
  const int g    = lane >> 4;      // k-group

  __shared__ __align__(16) u16 Ahi[2][MT][LD];
  __shared__ __align__(16) u16 Alo[2][MT][LD];
  __shared__ __align__(16) float Wsm[644];
  __shared__ __align__(16) float kS[7][MT][2];
  __shared__ __align__(16) float yL[MT][2];
  __shared__ __align__(16) float y5L[MT][2];
  __shared__ __align__(16) float pD[8][MT][2];
  __shared__ float red[8];

  // ---- one-time setup ----
  {
    const float* wp = ws + OFF_WPACK/4;
    Wsm[tid] = wp[tid];
    if (tid < 132) Wsm[512 + tid] = wp[512 + tid];
  }
  if (tid < 32) yL[tid >> 1][tid & 1] = x0[wg*32 + tid];

  // resident W2/W3 fragments (A-operand: row n = lane&15, k = g*8+e)
  const u16* w2th = (const u16*)((const char*)ws + OFF_W2TH);
  const u16* w2tl = (const u16*)((const char*)ws + OFF_W2TL);
  const u16* w3th = (const u16*)((const char*)ws + OFF_W3TH);
  const u16* w3tl = (const u16*)((const char*)ws + OFF_W3TL);
  short8 W2H[4], W2L[4], W3H[4], W3L[4];
  {
    const int nglob = wv*16 + nl;
#pragma unroll
    for (int ks = 0; ks < 4; ++ks) {
      int off = nglob*HID + ks*32 + g*8;
      W2H[ks] = *(const short8*)(w2th + off);
      W2L[ks] = *(const short8*)(w2tl + off);
      W3H[ks] = *(const short8*)(w3th + off);
      W3L[ks] = *(const short8*)(w3tl + off);
    }
  }
  // per-lane W4 slice: w4c[r][c] = W4[wv*16+g*4+r][c]
  float w4c[4][2];
#pragma unroll
  for (int r = 0; r < 4; ++r) {
    int n = wv*16 + g*4 + r;
    w4c[r][0] = W4g[n*2 + 0];
    w4c[r][1] = W4g[n*2 + 1];
  }
  __syncthreads();
  const f32x4 bv2 = *(const f32x4*)&Wsm[384 + wv*16 + g*4];
  const f32x4 bv3 = *(const f32x4*)&Wsm[512 + wv*16 + g*4];

  float* part = ws + OFF_PART/4;
  u32*  cnt   = (u32*)((char*)ws + OFF_CNT);

  float h = 0.5f * (t_arr[1] - t_arr[0]);
  float heff = h;

  // ---- phase A: inline stage combine (from pD) + L1 ----
  auto phaseA = [&](auto SC, int fromPD) {
    constexpr int S = decltype(SC)::v;
    const int m  = tid >> 5;        // 16 rows
    const int jc = tid & 31;        // 32 col-chunks of 4
    float ys0, ys1;
    const float y0 = yL[m][0], y1 = yL[m][1];
    if constexpr (S == 1) {
      ys0 = y0; ys1 = y1;
    } else {
      float kp0, kp1;
      if (S == 2 && !fromPD) {
        kp0 = kS[0][m][0]; kp1 = kS[0][m][1];
      } else {
        kp0 = Wsm[640]; kp1 = Wsm[641];
#pragma unroll
        for (int w = 0; w < 8; ++w) {
          f32x2 p = *(const f32x2*)&pD[w][m][0];
          kp0 += p[0]; kp1 += p[1];
        }
        if (jc < 2) kS[S-2][m][jc] = jc ? kp1 : kp0;
      }
      if constexpr (S == 2) {
        ys0 = fmaf(heff, CA21*kp0, y0);
        ys1 = fmaf(heff, CA21*kp1, y1);
      } else if constexpr (S == 3) {
        f32x2 k1 = *(const f32x2*)&kS[0][m][0];
        ys0 = fmaf(heff, CA31*k1[0] + CA32*kp0, y0);
        ys1 = fmaf(heff, CA31*k1[1] + CA32*kp1, y1);
      } else if constexpr (S == 4) {
        f32x2 k1 = *(const f32x2*)&kS[0][m][0];
        f32x2 k2 = *(const f32x2*)&kS[1][m][0];
        ys0 = fmaf(heff, CA41*k1[0] + CA42*k2[0] + CA43*kp0, y0);
        ys1 = fmaf(heff, CA41*k1[1] + CA42*k2[1] + CA43*kp1, y1);
      } else if constexpr (S == 5) {
        f32x2 k1 = *(const f32x2*)&kS[0][m][0];
        f32x2 k2 = *(const f32x2*)&kS[1][m][0];
        f32x2 k3 = *(const f32x2*)&kS[2][m][0];
        ys0 = fmaf(heff, CA51*k1[0] + CA52*k2[0] + CA53*k3[0] + CA54*kp0, y0);
        ys1 = fmaf(heff, CA51*k1[1] + CA52*k2[1] + CA53*k3[1] + CA54*kp1, y1);
      } else if constexpr (S == 6) {
        f32x2 k1 = *(const f32x2*)&kS[0][m][0];
        f32x2 k2 = *(const f32x2*)&kS[1][m][0];
        f32x2 k3 = *(const f32x2*)&kS[2][m][0];
        f32x2 k4 = *(const f32x2*)&kS[3][m][0];
        ys0 = fmaf(heff, CA61*k1[0] + CA62*k2[0] + CA63*k3[0] + CA64*k4[0] + CA65*kp0, y0);
        ys1 = fmaf(heff, CA61*k1[1] + CA62*k2[1] + CA63*k3[1] + CA64*k4[1] + CA65*kp1, y1);
      } else {  // S == 7: y5
        f32x2 k1 = *(const f32x2*)&kS[0][m][0];
        f32x2 k3 = *(const f32x2*)&kS[2][m][0];
        f32x2 k4 = *(const f32x2*)&kS[3][m][0];
        f32x2 k5 = *(const f32x2*)&kS[4][m][0];
        ys0 = fmaf(heff, CB1*k1[0] + CB3*k3[0] + CB4*k4[0] + CB5*k5[0] + CB6*kp0, y0);
        ys1 = fmaf(heff, CB1*k1[1] + CB3*k3[1] + CB4*k4[1] + CB5*k5[1] + CB6*kp1, y1);
        if (jc < 2) y5L[m][jc] = jc ? ys1 : ys0;
      }
    }
    // L1: 4 cols per thread
    const int j0 = jc * 4;
    f32x4 w0 = *(const f32x4*)&Wsm[j0];
    f32x4 w1 = *(const f32x4*)&Wsm[128 + j0];
    f32x4 bb = *(const f32x4*)&Wsm[256 + j0];
    float v0 = eluf(fmaf(ys1, w1[0], fmaf(ys0, w0[0], bb[0])));
    float v1 = eluf(fmaf(ys1, w1[1], fmaf(ys0, w0[1], bb[1])));
    float v2 = eluf(fmaf(ys1, w1[2], fmaf(ys0, w0[2], bb[2])));
    float v3 = eluf(fmaf(ys1, w1[3], fmaf(ys0, w0[3], bb[3])));
    u32 h01 = cvtpk(v0, v1), h23 = cvtpk(v2, v3);
    float l0 = v0 - __builtin_bit_cast(float, h01 << 16);
    float l1 = v1 - __builtin_bit_cast(float, h01 & 0xffff0000u);
    float l2 = v2 - __builtin_bit_cast(float, h23 << 16);
    float l3 = v3 - __builtin_bit_cast(float, h23 & 0xffff0000u);
    u32x2 hp = {h01, h23};
    u32x2 lp = {cvtpk(l0, l1), cvtpk(l2, l3)};
    *(u32x2*)&Ahi[0][m][j0] = hp;
    *(u32x2*)&Alo[0][m][j0] = lp;
  };

  // ---- L2: plane0 -> plane1, pack epilogue ----
  auto mmL2 = [&]() {
    f32x4 a0 = bv2, a1 = {0,0,0,0}, a2 = {0,0,0,0};
    __builtin_amdgcn_s_setprio(1);
#pragma unroll
    for (int ks = 0; ks < 4; ++ks) {
      short8 bh = *(const short8*)&Ahi[0][nl][ks*32 + g*8];
      short8 bl = *(const short8*)&Alo[0][nl][ks*32 + g*8];
      a0 = __builtin_amdgcn_mfma_f32_16x16x32_bf16(W2H[ks], bh, a0, 0, 0, 0);
      a1 = __builtin_amdgcn_mfma_f32_16x16x32_bf16(W2L[ks], bh, a1, 0, 0, 0);
      a2 = __builtin_amdgcn_mfma_f32_16x16x32_bf16(W2H[ks], bl, a2, 0, 0, 0);
    }
    __builtin_amdgcn_s_setprio(0);
    float v0 = eluf(a0[0] + a1[0] + a2[0]);
    float v1 = eluf(a0[1] + a1[1] + a2[1]);
    float v2 = eluf(a0[2] + a1[2] + a2[2]);
    float v3 = eluf(a0[3] + a1[3] + a2[3]);
    u32 h01 = cvtpk(v0, v1), h23 = cvtpk(v2, v3);
    float l0 = v0 - __builtin_bit_cast(float, h01 << 16);
    float l1 = v1 - __builtin_bit_cast(float, h01 & 0xffff0000u);
    float l2 = v2 - __builtin_bit_cast(float, h23 << 16);
    float l3 = v3 - __builtin_bit_cast(float, h23 & 0xffff0000u);
    u32x2 hp = {h01, h23};
    u32x2 lp = {cvtpk(l0, l1), cvtpk(l2, l3)};
    const int n0 = wv*16 + g*4;
    *(u32x2*)&Ahi[1][nl][n0] = hp;
    *(u32x2*)&Alo[1][nl][n0] = lp;
  };

  // ---- L3 + fused L4 dot -> pD ----
  auto mmL3 = [&]() {
    f32x4 a0 = bv3, a1 = {0,0,0,0}, a2 = {0,0,0,0};
    __builtin_amdgcn_s_setprio(1);
#pragma unroll
    for (int ks = 0; ks < 4; ++ks) {
      short8 bh = *(const short8*)&Ahi[1][nl][ks*32 + g*8];
      short8 bl = *(const short8*)&Alo[1][nl][ks*32 + g*8];
      a0 = __builtin_amdgcn_mfma_f32_16x16x32_bf16(W3H[ks], bh, a0, 0, 0, 0);
      a1 = __builtin_amdgcn_mfma_f32_16x16x32_bf16(W3L[ks], bh, a1, 0, 0, 0);
      a2 = __builtin_amdgcn_mfma_f32_16x16x32_bf16(W3H[ks], bl, a2, 0, 0, 0);
    }
    __builtin_amdgcn_s_setprio(0);
    float v0 = eluf(a0[0] + a1[0] + a2[0]);
    float v1 = eluf(a0[1] + a1[1] + a2[1]);
    float v2 = eluf(a0[2] + a1[2] + a2[2]);
    float v3 = eluf(a0[3] + a1[3] + a2[3]);
    float p0 = v0*w4c[0][0] + v1*w4c[1][0] + v2*w4c[2][0] + v3*w4c[3][0];
    float p1 = v0*w4c[0][1] + v1*w4c[1][1] + v2*w4c[2][1] + v3*w4c[3][1];
    p0 += __shfl_xor(p0, 16); p0 += __shfl_xor(p0, 32);
    p1 += __shfl_xor(p1, 16); p1 += __shfl_xor(p1, 32);
    if (lane < 16) {
      f32x2 pp = {p0, p1};
      *(f32x2*)&pD[wv][lane][0] = pp;
    }
  };

  // ---- main adaptive loop ----
  for (int iv = 0; iv < 7; ++iv) {
    const float t1 = t_arr[iv + 1];
    float tc = t_arr[iv];
    for (int s = 0; s < 8; ++s) {
      const int step = iv*8 + s;
      float rem = t1 - tc;
      if (rem <= 1e-9f) break;          // uniform across all WGs
      heff = fminf(h, rem);

      if (iv == 0 && s == 0) {          // fresh k1 eval
        phaseA(IC<1>{}, 0); __syncthreads();
        mmL2(); __syncthreads();
        mmL3(); __syncthreads();
        phaseA(IC<2>{}, 1);
      } else {
        phaseA(IC<2>{}, 0);             // FSAL: k1 = kS[0]
      }
      __syncthreads(); mmL2(); __syncthreads(); mmL3(); __syncthreads();
      phaseA(IC<3>{}, 1); __syncthreads(); mmL2(); __syncthreads(); mmL3(); __syncthreads();
      phaseA(IC<4>{}, 1); __syncthreads(); mmL2(); __syncthreads(); mmL3(); __syncthreads();
      phaseA(IC<5>{}, 1); __syncthreads(); mmL2(); __syncthreads(); mmL3(); __syncthreads();
      phaseA(IC<6>{}, 1); __syncthreads(); mmL2(); __syncthreads(); mmL3(); __syncthreads();
      phaseA(IC<7>{}, 1); __syncthreads(); mmL2(); __syncthreads(); mmL3(); __syncthreads();
      // pD now holds k7 partials

      // ---- error partial (wave 0) + publish ----
      if (wv == 0 && lane < 32) {
        int m = lane >> 1, c = lane & 1;
        float kp = Wsm[640 + c];
#pragma unroll
        for (int w = 0; w < 8; ++w) kp += pD[w][m][c];
        kS[6][m][c] = kp;
        float e = heff * (CE1*kS[0][m][c] + CE3*kS[2][m][c] + CE4*kS[3][m][c]
                        + CE5*kS[4][m][c] + CE6*kS[5][m][c] + CE7*kp);
        float tol = 1e-4f + 1e-3f * fmaxf(fabsf(yL[m][c]), fabsf(y5L[m][c]));
        float rr = e / tol;
        float es = rr * rr;
#pragma unroll
        for (int mk = 1; mk < 32; mk <<= 1) es += __shfl_xor(es, mk);
        if (lane == 0) {
          __hip_atomic_store(&part[(step & 1)*NWG + wg], es, __ATOMIC_RELAXED, __HIP_MEMORY_SCOPE_AGENT);
          __hip_atomic_fetch_add(&cnt[step], 1u, __ATOMIC_RELEASE, __HIP_MEMORY_SCOPE_AGENT);
        }
      }
      if (tid == 0) {
        while (__hip_atomic_load(&cnt[step], __ATOMIC_ACQUIRE, __HIP_MEMORY_SCOPE_AGENT) < (u32)NWG)
          __builtin_amdgcn_s_sleep(2);
      }
      __syncthreads();
      // ---- symmetric deterministic reduce (every WG, fixed order) ----
      float pv = __hip_atomic_load(&part[(step & 1)*NWG + tid], __ATOMIC_RELAXED, __HIP_MEMORY_SCOPE_AGENT);
#pragma unroll
      for (int mk = 1; mk < 64; mk <<= 1) pv += __shfl_xor(pv, mk);
      if (lane == 0) red[wv] = pv;
      __syncthreads();
      float err_norm = sqrtf((red[0] + red[1] + red[2] + red[3]
                            + red[4] + red[5] + red[6] + red[7]) * (1.0f/16384.f));
      bool acc = (err_norm <= 1.0f);
      float factor = fminf(10.f, fmaxf(0.2f, 0.9f * powf(fmaxf(err_norm, 1e-10f), -0.2f)));
      if (acc) {
        if (tid < 32) { int m = tid >> 1, c = tid & 1;
          yL[m][c] = y5L[m][c];
          kS[0][m][c] = kS[6][m][c];     // FSAL: k1 <- k7
        }
        tc += heff;
      }
      h = heff * factor;
      __syncthreads();
    }
    if (tid < 32)
      out[(size_t)(iv + 1) * 16384 + wg*32 + tid] = yL[tid >> 1][tid & 1];
  }
}

extern "C" void kernel_launch(void* const* d_in, const int* in_sizes, int n_in,
                              void* d_out, int out_size, void* d_ws, size_t ws_size,
                              hipStream_t stream)
{
  const float* x0 = (const float*)d_in[0];
  const float* t  = (const float*)d_in[1];
  const float* W1 = (const float*)d_in[2];
  const float* b1 = (const float*)d_in[3];
  const float* W2 = (const float*)d_in[4];
  const float* b2 = (const float*)d_in[5];
  const float* W3 = (const float*)d_in[6];
  const float* b3 = (const float*)d_in[7];
  const float* W4 = (const float*)d_in[8];
  const float* b4 = (const float*)d_in[9];
  float* out = (float*)d_out;
  float* ws  = (float*)d_ws;

  prologue<<<64, 256, 0, stream>>>(x0, t, W1, b1, W2, b2, W3, b3, W4, b4, ws, out);
  solver<<<NWG, NTHR, 0, stream>>>(x0, t, W4, ws, out);
}

// Round 6
// 433.607 us; speedup vs baseline: 1.0231x; 1.0231x over previous
//
#include <hip/hip_runtime.h>
#include <stdint.h>

typedef unsigned int u32;
typedef unsigned short u16;
typedef float f32x4 __attribute__((ext_vector_type(4)));
typedef float f32x2 __attribute__((ext_vector_type(2)));
typedef short short8 __attribute__((ext_vector_type(8)));
typedef unsigned short ushort8 __attribute__((ext_vector_type(8)));
typedef unsigned int u32x2 __attribute__((ext_vector_type(2)));
typedef unsigned int u32x4 __attribute__((ext_vector_type(4)));

#define HID  128
#define MT   16        // batch rows per WG
#define NWG  512       // 8192/16, 2 WGs per CU -> co-resident (22KB LDS, <=128 VGPR)
#define NTHR 512       // 8 waves
#define LD   136       // LDS plane stride in u16 (272B rows)

// ---- ws byte offsets ----
#define OFF_PART  0        // 2 x 512 f32 (parity double-buffered)
#define OFF_CNT   4096     // 64 u32
#define OFF_WPACK 8192     // 644 f32: W1(256) b1(128) b2(128) b3(128) b4(2)
#define OFF_W2TH  16384    // 128x128 bf16 [n][k] hi
#define OFF_W2TL  49152
#define OFF_W3TH  81920
#define OFF_W3TL  114688

constexpr float CA21 = (float)(1.0/5.0);
constexpr float CA31 = (float)(3.0/40.0),   CA32 = (float)(9.0/40.0);
constexpr float CA41 = (float)(44.0/45.0),  CA42 = (float)(-56.0/15.0), CA43 = (float)(32.0/9.0);
constexpr float CA51 = (float)(19372.0/6561.0), CA52 = (float)(-25360.0/2187.0);
constexpr float CA53 = (float)(64448.0/6561.0), CA54 = (float)(-212.0/729.0);
constexpr float CA61 = (float)(9017.0/3168.0),  CA62 = (float)(-355.0/33.0);
constexpr float CA63 = (float)(46732.0/5247.0), CA64 = (float)(49.0/176.0), CA65 = (float)(-5103.0/18656.0);
constexpr float CB1 = (float)(35.0/384.0), CB3 = (float)(500.0/1113.0), CB4 = (float)(125.0/192.0);
constexpr float CB5 = (float)(-2187.0/6784.0), CB6 = (float)(11.0/84.0);
constexpr float CE1 = (float)(35.0/384.0 - 5179.0/57600.0);
constexpr float CE3 = (float)(500.0/1113.0 - 7571.0/16695.0);
constexpr float CE4 = (float)(125.0/192.0 - 393.0/640.0);
constexpr float CE5 = (float)(-2187.0/6784.0 + 92097.0/339200.0);
constexpr float CE6 = (float)(11.0/84.0 - 187.0/2100.0);
constexpr float CE7 = (float)(-1.0/40.0);

template<int N> struct IC { static constexpr int v = N; };

__device__ __forceinline__ u16 f2bf(float x) {
  u32 u = __builtin_bit_cast(u32, x);
  u32 r = (u + 0x7FFFu + ((u >> 16) & 1u)) >> 16;
  return (u16)r;
}
__device__ __forceinline__ float bf2f(u16 b) {
  u32 u = ((u32)b) << 16;
  return __builtin_bit_cast(float, u);
}
__device__ __forceinline__ float eluf(float x) {
  return x > 0.f ? x : (__expf(x) - 1.f);
}
// v_cvt_pk_bf16_f32: dst[15:0]=bf16(a), dst[31:16]=bf16(b) (RNE)
__device__ __forceinline__ u32 cvtpk(float a, float b) {
  u32 r; asm("v_cvt_pk_bf16_f32 %0, %1, %2" : "=v"(r) : "v"(a), "v"(b)); return r;
}

// ---------------------------------------------------------------------------
// Prologue
// ---------------------------------------------------------------------------
__global__ void prologue(const float* __restrict__ x0, const float* __restrict__ t,
                         const float* __restrict__ W1, const float* __restrict__ b1,
                         const float* __restrict__ W2, const float* __restrict__ b2,
                         const float* __restrict__ W3, const float* __restrict__ b3,
                         const float* __restrict__ W4, const float* __restrict__ b4,
                         float* __restrict__ ws, float* __restrict__ out)
{
  int gid = blockIdx.x * blockDim.x + threadIdx.x;   // 64*256 = 16384
  out[gid] = x0[gid];
  {
    int k = gid >> 7, j = gid & 127;
    u16* w2th = (u16*)((char*)ws + OFF_W2TH);
    u16* w2tl = (u16*)((char*)ws + OFF_W2TL);
    u16* w3th = (u16*)((char*)ws + OFF_W3TH);
    u16* w3tl = (u16*)((char*)ws + OFF_W3TL);
    float w = W2[gid];
    u16 hb = f2bf(w);
    w2th[j*HID + k] = hb;
    w2tl[j*HID + k] = f2bf(w - bf2f(hb));
    w = W3[gid];
    hb = f2bf(w);
    w3th[j*HID + k] = hb;
    w3tl[j*HID + k] = f2bf(w - bf2f(hb));
  }
  float* wp = ws + OFF_WPACK/4;
  if (gid < 256) wp[gid] = W1[gid];
  if (gid < 128) {
    wp[256 + gid] = b1[gid];
    wp[384 + gid] = b2[gid];
    wp[512 + gid] = b3[gid];
  }
  if (gid < 2)  wp[640 + gid] = b4[gid];
  if (gid < 64) ((u32*)((char*)ws + OFF_CNT))[gid] = 0u;
}

// ---------------------------------------------------------------------------
// Persistent solver: 512 WGs x 512 threads, 2 WGs per CU.
// waves_per_eu(4,4): min=4 guarantees <=128 VGPR (2 blocks/CU co-resident,
// spin-sync safe); max=4 stops the allocator from targeting 8 waves/SIMD
// (round 5: it chose 64 VGPR and spilled the resident weight fragments).
// ---------------------------------------------------------------------------
__global__ void
__attribute__((amdgpu_flat_work_group_size(NTHR, NTHR), amdgpu_waves_per_eu(4, 4)))
solver(const float* __restrict__ x0, const float* __restrict__ t_arr,
       const float* __restrict__ W4g, float* __restrict__ ws,
       float* __restrict__ out)
{
  const int tid  = threadIdx.x;
  const int wg   = blockIdx.x;
  const int lane = tid & 63;
  const int wv   = tid >> 6;
  const int nl   = lane & 15;      // MFMA fragment index
  const int g    = lane >> 4;      // k-group

  __shared__ __align__(16) u16 Ahi[2][MT][LD];
  __shared__ __align__(16) u16 Alo[2][MT][LD];
  __shared__ __align__(16) float Wsm[644];
  __shared__ __align__(16) float kS[7][MT][2];
  __shared__ __align__(16) float yL[MT][2];
  __shared__ __align__(16) float y5L[MT][2];
  __shared__ __align__(16) float pD[8][MT][2];
  __shared__ float red[8];

  // ---- one-time setup ----
  {
    const float* wp = ws + OFF_WPACK/4;
    Wsm[tid] = wp[tid];
    if (tid < 132) Wsm[512 + tid] = wp[512 + tid];
  }
  if (tid < 32) yL[tid >> 1][tid & 1] = x0[wg*32 + tid];

  // resident W2/W3 fragments (A-operand: row n = lane&15, k = g*8+e)
  const u16* w2th = (const u16*)((const char*)ws + OFF_W2TH);
  const u16* w2tl = (const u16*)((const char*)ws + OFF_W2TL);
  const u16* w3th = (const u16*)((const char*)ws + OFF_W3TH);
  const u16* w3tl = (const u16*)((const char*)ws + OFF_W3TL);
  short8 W2H[4], W2L[4], W3H[4], W3L[4];
  {
    const int nglob = wv*16 + nl;
#pragma unroll
    for (int ks = 0; ks < 4; ++ks) {
      int off = nglob*HID + ks*32 + g*8;
      W2H[ks] = *(const short8*)(w2th + off);
      W2L[ks] = *(const short8*)(w2tl + off);
      W3H[ks] = *(const short8*)(w3th + off);
      W3L[ks] = *(const short8*)(w3tl + off);
    }
  }
  // per-lane W4 slice: w4c[r][c] = W4[wv*16+g*4+r][c]
  float w4c[4][2];
#pragma unroll
  for (int r = 0; r < 4; ++r) {
    int n = wv*16 + g*4 + r;
    w4c[r][0] = W4g[n*2 + 0];
    w4c[r][1] = W4g[n*2 + 1];
  }
  __syncthreads();
  const f32x4 bv2 = *(const f32x4*)&Wsm[384 + wv*16 + g*4];
  const f32x4 bv3 = *(const f32x4*)&Wsm[512 + wv*16 + g*4];

  float* part = ws + OFF_PART/4;
  u32*  cnt   = (u32*)((char*)ws + OFF_CNT);

  float h = 0.5f * (t_arr[1] - t_arr[0]);
  float heff = h;

  // ---- phase A: inline stage combine (from pD) + L1 ----
  auto phaseA = [&](auto SC, int fromPD) {
    constexpr int S = decltype(SC)::v;
    const int m  = tid >> 5;        // 16 rows
    const int jc = tid & 31;        // 32 col-chunks of 4
    float ys0, ys1;
    const float y0 = yL[m][0], y1 = yL[m][1];
    if constexpr (S == 1) {
      ys0 = y0; ys1 = y1;
    } else {
      float kp0, kp1;
      if (S == 2 && !fromPD) {
        kp0 = kS[0][m][0]; kp1 = kS[0][m][1];
      } else {
        kp0 = Wsm[640]; kp1 = Wsm[641];
#pragma unroll
        for (int w = 0; w < 8; ++w) {
          f32x2 p = *(const f32x2*)&pD[w][m][0];
          kp0 += p[0]; kp1 += p[1];
        }
        if (jc < 2) kS[S-2][m][jc] = jc ? kp1 : kp0;
      }
      if constexpr (S == 2) {
        ys0 = fmaf(heff, CA21*kp0, y0);
        ys1 = fmaf(heff, CA21*kp1, y1);
      } else if constexpr (S == 3) {
        f32x2 k1 = *(const f32x2*)&kS[0][m][0];
        ys0 = fmaf(heff, CA31*k1[0] + CA32*kp0, y0);
        ys1 = fmaf(heff, CA31*k1[1] + CA32*kp1, y1);
      } else if constexpr (S == 4) {
        f32x2 k1 = *(const f32x2*)&kS[0][m][0];
        f32x2 k2 = *(const f32x2*)&kS[1][m][0];
        ys0 = fmaf(heff, CA41*k1[0] + CA42*k2[0] + CA43*kp0, y0);
        ys1 = fmaf(heff, CA41*k1[1] + CA42*k2[1] + CA43*kp1, y1);
      } else if constexpr (S == 5) {
        f32x2 k1 = *(const f32x2*)&kS[0][m][0];
        f32x2 k2 = *(const f32x2*)&kS[1][m][0];
        f32x2 k3 = *(const f32x2*)&kS[2][m][0];
        ys0 = fmaf(heff, CA51*k1[0] + CA52*k2[0] + CA53*k3[0] + CA54*kp0, y0);
        ys1 = fmaf(heff, CA51*k1[1] + CA52*k2[1] + CA53*k3[1] + CA54*kp1, y1);
      } else if constexpr (S == 6) {
        f32x2 k1 = *(const f32x2*)&kS[0][m][0];
        f32x2 k2 = *(const f32x2*)&kS[1][m][0];
        f32x2 k3 = *(const f32x2*)&kS[2][m][0];
        f32x2 k4 = *(const f32x2*)&kS[3][m][0];
        ys0 = fmaf(heff, CA61*k1[0] + CA62*k2[0] + CA63*k3[0] + CA64*k4[0] + CA65*kp0, y0);
        ys1 = fmaf(heff, CA61*k1[1] + CA62*k2[1] + CA63*k3[1] + CA64*k4[1] + CA65*kp1, y1);
      } else {  // S == 7: y5
        f32x2 k1 = *(const f32x2*)&kS[0][m][0];
        f32x2 k3 = *(const f32x2*)&kS[2][m][0];
        f32x2 k4 = *(const f32x2*)&kS[3][m][0];
        f32x2 k5 = *(const f32x2*)&kS[4][m][0];
        ys0 = fmaf(heff, CB1*k1[0] + CB3*k3[0] + CB4*k4[0] + CB5*k5[0] + CB6*kp0, y0);
        ys1 = fmaf(heff, CB1*k1[1] + CB3*k3[1] + CB4*k4[1] + CB5*k5[1] + CB6*kp1, y1);
        if (jc < 2) y5L[m][jc] = jc ? ys1 : ys0;
      }
    }
    // L1: 4 cols per thread
    const int j0 = jc * 4;
    f32x4 w0 = *(const f32x4*)&Wsm[j0];
    f32x4 w1 = *(const f32x4*)&Wsm[128 + j0];
    f32x4 bb = *(const f32x4*)&Wsm[256 + j0];
    float v0 = eluf(fmaf(ys1, w1[0], fmaf(ys0, w0[0], bb[0])));
    float v1 = eluf(fmaf(ys1, w1[1], fmaf(ys0, w0[1], bb[1])));
    float v2 = eluf(fmaf(ys1, w1[2], fmaf(ys0, w0[2], bb[2])));
    float v3 = eluf(fmaf(ys1, w1[3], fmaf(ys0, w0[3], bb[3])));
    u32 h01 = cvtpk(v0, v1), h23 = cvtpk(v2, v3);
    float l0 = v0 - __builtin_bit_cast(float, h01 << 16);
    float l1 = v1 - __builtin_bit_cast(float, h01 & 0xffff0000u);
    float l2 = v2 - __builtin_bit_cast(float, h23 << 16);
    float l3 = v3 - __builtin_bit_cast(float, h23 & 0xffff0000u);
    u32x2 hp = {h01, h23};
    u32x2 lp = {cvtpk(l0, l1), cvtpk(l2, l3)};
    *(u32x2*)&Ahi[0][m][j0] = hp;
    *(u32x2*)&Alo[0][m][j0] = lp;
  };

  // ---- L2: plane0 -> plane1, pack epilogue ----
  auto mmL2 = [&]() {
    f32x4 a0 = bv2, a1 = {0,0,0,0}, a2 = {0,0,0,0};
    __builtin_amdgcn_s_setprio(1);
#pragma unroll
    for (int ks = 0; ks < 4; ++ks) {
      short8 bh = *(const short8*)&Ahi[0][nl][ks*32 + g*8];
      short8 bl = *(const short8*)&Alo[0][nl][ks*32 + g*8];
      a0 = __builtin_amdgcn_mfma_f32_16x16x32_bf16(W2H[ks], bh, a0, 0, 0, 0);
      a1 = __builtin_amdgcn_mfma_f32_16x16x32_bf16(W2L[ks], bh, a1, 0, 0, 0);
      a2 = __builtin_amdgcn_mfma_f32_16x16x32_bf16(W2H[ks], bl, a2, 0, 0, 0);
    }
    __builtin_amdgcn_s_setprio(0);
    float v0 = eluf(a0[0] + a1[0] + a2[0]);
    float v1 = eluf(a0[1] + a1[1] + a2[1]);
    float v2 = eluf(a0[2] + a1[2] + a2[2]);
    float v3 = eluf(a0[3] + a1[3] + a2[3]);
    u32 h01 = cvtpk(v0, v1), h23 = cvtpk(v2, v3);
    float l0 = v0 - __builtin_bit_cast(float, h01 << 16);
    float l1 = v1 - __builtin_bit_cast(float, h01 & 0xffff0000u);
    float l2 = v2 - __builtin_bit_cast(float, h23 << 16);
    float l3 = v3 - __builtin_bit_cast(float, h23 & 0xffff0000u);
    u32x2 hp = {h01, h23};
    u32x2 lp = {cvtpk(l0, l1), cvtpk(l2, l3)};
    const int n0 = wv*16 + g*4;
    *(u32x2*)&Ahi[1][nl][n0] = hp;
    *(u32x2*)&Alo[1][nl][n0] = lp;
  };

  // ---- L3 + fused L4 dot -> pD ----
  auto mmL3 = [&]() {
    f32x4 a0 = bv3, a1 = {0,0,0,0}, a2 = {0,0,0,0};
    __builtin_amdgcn_s_setprio(1);
#pragma unroll
    for (int ks = 0; ks < 4; ++ks) {
      short8 bh = *(const short8*)&Ahi[1][nl][ks*32 + g*8];
      short8 bl = *(const short8*)&Alo[1][nl][ks*32 + g*8];
      a0 = __builtin_amdgcn_mfma_f32_16x16x32_bf16(W3H[ks], bh, a0, 0, 0, 0);
      a1 = __builtin_amdgcn_mfma_f32_16x16x32_bf16(W3L[ks], bh, a1, 0, 0, 0);
      a2 = __builtin_amdgcn_mfma_f32_16x16x32_bf16(W3H[ks], bl, a2, 0, 0, 0);
    }
    __builtin_amdgcn_s_setprio(0);
    float v0 = eluf(a0[0] + a1[0] + a2[0]);
    float v1 = eluf(a0[1] + a1[1] + a2[1]);
    float v2 = eluf(a0[2] + a1[2] + a2[2]);
    float v3 = eluf(a0[3] + a1[3] + a2[3]);
    float p0 = v0*w4c[0][0] + v1*w4c[1][0] + v2*w4c[2][0] + v3*w4c[3][0];
    float p1 = v0*w4c[0][1] + v1*w4c[1][1] + v2*w4c[2][1] + v3*w4c[3][1];
    p0 += __shfl_xor(p0, 16); p0 += __shfl_xor(p0, 32);
    p1 += __shfl_xor(p1, 16); p1 += __shfl_xor(p1, 32);
    if (lane < 16) {
      f32x2 pp = {p0, p1};
      *(f32x2*)&pD[wv][lane][0] = pp;
    }
  };

  // ---- main adaptive loop ----
  for (int iv = 0; iv < 7; ++iv) {
    const float t1 = t_arr[iv + 1];
    float tc = t_arr[iv];
    for (int s = 0; s < 8; ++s) {
      const int step = iv*8 + s;
      float rem = t1 - tc;
      if (rem <= 1e-9f) break;          // uniform across all WGs
      heff = fminf(h, rem);

      if (iv == 0 && s == 0) {          // fresh k1 eval
        phaseA(IC<1>{}, 0); __syncthreads();
        mmL2(); __syncthreads();
        mmL3(); __syncthreads();
        phaseA(IC<2>{}, 1);
      } else {
        phaseA(IC<2>{}, 0);             // FSAL: k1 = kS[0]
      }
      __syncthreads(); mmL2(); __syncthreads(); mmL3(); __syncthreads();
      phaseA(IC<3>{}, 1); __syncthreads(); mmL2(); __syncthreads(); mmL3(); __syncthreads();
      phaseA(IC<4>{}, 1); __syncthreads(); mmL2(); __syncthreads(); mmL3(); __syncthreads();
      phaseA(IC<5>{}, 1); __syncthreads(); mmL2(); __syncthreads(); mmL3(); __syncthreads();
      phaseA(IC<6>{}, 1); __syncthreads(); mmL2(); __syncthreads(); mmL3(); __syncthreads();
      phaseA(IC<7>{}, 1); __syncthreads(); mmL2(); __syncthreads(); mmL3(); __syncthreads();
      // pD now holds k7 partials

      // ---- error partial (wave 0) + publish ----
      if (wv == 0 && lane < 32) {
        int m = lane >> 1, c = lane & 1;
        float kp = Wsm[640 + c];
#pragma unroll
        for (int w = 0; w < 8; ++w) kp += pD[w][m][c];
        kS[6][m][c] = kp;
        float e = heff * (CE1*kS[0][m][c] + CE3*kS[2][m][c] + CE4*kS[3][m][c]
                        + CE5*kS[4][m][c] + CE6*kS[5][m][c] + CE7*kp);
        float tol = 1e-4f + 1e-3f * fmaxf(fabsf(yL[m][c]), fabsf(y5L[m][c]));
        float rr = e / tol;
        float es = rr * rr;
#pragma unroll
        for (int mk = 1; mk < 32; mk <<= 1) es += __shfl_xor(es, mk);
        if (lane == 0) {
          __hip_atomic_store(&part[(step & 1)*NWG + wg], es, __ATOMIC_RELAXED, __HIP_MEMORY_SCOPE_AGENT);
          __hip_atomic_fetch_add(&cnt[step], 1u, __ATOMIC_RELEASE, __HIP_MEMORY_SCOPE_AGENT);
        }
      }
      if (tid == 0) {
        while (__hip_atomic_load(&cnt[step], __ATOMIC_ACQUIRE, __HIP_MEMORY_SCOPE_AGENT) < (u32)NWG)
          __builtin_amdgcn_s_sleep(2);
      }
      __syncthreads();
      // ---- symmetric deterministic reduce (every WG, fixed order) ----
      float pv = __hip_atomic_load(&part[(step & 1)*NWG + tid], __ATOMIC_RELAXED, __HIP_MEMORY_SCOPE_AGENT);
#pragma unroll
      for (int mk = 1; mk < 64; mk <<= 1) pv += __shfl_xor(pv, mk);
      if (lane == 0) red[wv] = pv;
      __syncthreads();
      float err_norm = sqrtf((red[0] + red[1] + red[2] + red[3]
                            + red[4] + red[5] + red[6] + red[7]) * (1.0f/16384.f));
      bool acc = (err_norm <= 1.0f);
      float factor = fminf(10.f, fmaxf(0.2f, 0.9f * powf(fmaxf(err_norm, 1e-10f), -0.2f)));
      if (acc) {
        if (tid < 32) { int m = tid >> 1, c = tid & 1;
          yL[m][c] = y5L[m][c];
          kS[0][m][c] = kS[6][m][c];     // FSAL: k1 <- k7
        }
        tc += heff;
      }
      h = heff * factor;
      __syncthreads();
    }
    if (tid < 32)
      out[(size_t)(iv + 1) * 16384 + wg*32 + tid] = yL[tid >> 1][tid & 1];
  }
}

extern "C" void kernel_launch(void* const* d_in, const int* in_sizes, int n_in,
                              void* d_out, int out_size, void* d_ws, size_t ws_size,
                              hipStream_t stream)
{
  const float* x0 = (const float*)d_in[0];
  const float* t  = (const float*)d_in[1];
  const float* W1 = (const float*)d_in[2];
  const float* b1 = (const float*)d_in[3];
  const float* W2 = (const float*)d_in[4];
  const float* b2 = (const float*)d_in[5];
  const float* W3 = (const float*)d_in[6];
  const float* b3 = (const float*)d_in[7];
  const float* W4 = (const float*)d_in[8];
  const float* b4 = (const float*)d_in[9];
  float* out = (float*)d_out;
  float* ws  = (float*)d_ws;

  prologue<<<64, 256, 0, stream>>>(x0, t, W1, b1, W2, b2, W3, b3, W4, b4, ws, out);
  solver<<<NWG, NTHR, 0, stream>>>(x0, t, W4, ws, out);
}

// Round 7
// 428.826 us; speedup vs baseline: 1.0345x; 1.0112x over previous
//
#include <hip/hip_runtime.h>
#include <stdint.h>

typedef unsigned int u32;
typedef unsigned short u16;
typedef float f32x4 __attribute__((ext_vector_type(4)));
typedef float f32x2 __attribute__((ext_vector_type(2)));
typedef short short8 __attribute__((ext_vector_type(8)));
typedef unsigned short ushort8 __attribute__((ext_vector_type(8)));
typedef unsigned int u32x2 __attribute__((ext_vector_type(2)));
typedef unsigned int u32x4 __attribute__((ext_vector_type(4)));

#define HID  128
#define MT   16        // batch rows per WG
#define NWG  512       // 8192/16, 2 WGs per CU -> co-resident
#define NTHR 512       // 8 waves
#define LD   136       // LDS plane stride in u16 (272B rows)

// ---- ws byte offsets ----
#define OFF_PART  0        // 2 x 512 f32 (parity double-buffered)
#define OFF_CNT   4096     // 64 u32
#define OFF_WPACK 8192     // 644 f32: W1(256) b1(128) b2(128) b3(128) b4(2)
#define OFF_W2TH  16384    // 128x128 bf16 [n][k] hi
#define OFF_W2TL  49152
#define OFF_W3TH  81920
#define OFF_W3TL  114688

constexpr float CA21 = (float)(1.0/5.0);
constexpr float CA31 = (float)(3.0/40.0),   CA32 = (float)(9.0/40.0);
constexpr float CA41 = (float)(44.0/45.0),  CA42 = (float)(-56.0/15.0), CA43 = (float)(32.0/9.0);
constexpr float CA51 = (float)(19372.0/6561.0), CA52 = (float)(-25360.0/2187.0);
constexpr float CA53 = (float)(64448.0/6561.0), CA54 = (float)(-212.0/729.0);
constexpr float CA61 = (float)(9017.0/3168.0),  CA62 = (float)(-355.0/33.0);
constexpr float CA63 = (float)(46732.0/5247.0), CA64 = (float)(49.0/176.0), CA65 = (float)(-5103.0/18656.0);
constexpr float CB1 = (float)(35.0/384.0), CB3 = (float)(500.0/1113.0), CB4 = (float)(125.0/192.0);
constexpr float CB5 = (float)(-2187.0/6784.0), CB6 = (float)(11.0/84.0);
constexpr float CE1 = (float)(35.0/384.0 - 5179.0/57600.0);
constexpr float CE3 = (float)(500.0/1113.0 - 7571.0/16695.0);
constexpr float CE4 = (float)(125.0/192.0 - 393.0/640.0);
constexpr float CE5 = (float)(-2187.0/6784.0 + 92097.0/339200.0);
constexpr float CE6 = (float)(11.0/84.0 - 187.0/2100.0);
constexpr float CE7 = (float)(-1.0/40.0);

template<int N> struct IC { static constexpr int v = N; };

__device__ __forceinline__ u16 f2bf(float x) {
  u32 u = __builtin_bit_cast(u32, x);
  u32 r = (u + 0x7FFFu + ((u >> 16) & 1u)) >> 16;
  return (u16)r;
}
__device__ __forceinline__ float bf2f(u16 b) {
  u32 u = ((u32)b) << 16;
  return __builtin_bit_cast(float, u);
}
__device__ __forceinline__ float eluf(float x) {
  return x > 0.f ? x : (__expf(x) - 1.f);
}
// v_cvt_pk_bf16_f32: dst[15:0]=bf16(a), dst[31:16]=bf16(b) (RNE)
__device__ __forceinline__ u32 cvtpk(float a, float b) {
  u32 r; asm("v_cvt_pk_bf16_f32 %0, %1, %2" : "=v"(r) : "v"(a), "v"(b)); return r;
}

// ---------------------------------------------------------------------------
// Prologue
// ---------------------------------------------------------------------------
__global__ void prologue(const float* __restrict__ x0, const float* __restrict__ t,
                         const float* __restrict__ W1, const float* __restrict__ b1,
                         const float* __restrict__ W2, const float* __restrict__ b2,
                         const float* __restrict__ W3, const float* __restrict__ b3,
                         const float* __restrict__ W4, const float* __restrict__ b4,
                         float* __restrict__ ws, float* __restrict__ out)
{
  int gid = blockIdx.x * blockDim.x + threadIdx.x;   // 64*256 = 16384
  out[gid] = x0[gid];
  {
    int k = gid >> 7, j = gid & 127;
    u16* w2th = (u16*)((char*)ws + OFF_W2TH);
    u16* w2tl = (u16*)((char*)ws + OFF_W2TL);
    u16* w3th = (u16*)((char*)ws + OFF_W3TH);
    u16* w3tl = (u16*)((char*)ws + OFF_W3TL);
    float w = W2[gid];
    u16 hb = f2bf(w);
    w2th[j*HID + k] = hb;
    w2tl[j*HID + k] = f2bf(w - bf2f(hb));
    w = W3[gid];
    hb = f2bf(w);
    w3th[j*HID + k] = hb;
    w3tl[j*HID + k] = f2bf(w - bf2f(hb));
  }
  float* wp = ws + OFF_WPACK/4;
  if (gid < 256) wp[gid] = W1[gid];
  if (gid < 128) {
    wp[256 + gid] = b1[gid];
    wp[384 + gid] = b2[gid];
    wp[512 + gid] = b3[gid];
  }
  if (gid < 2)  wp[640 + gid] = b4[gid];
  if (gid < 64) ((u32*)((char*)ws + OFF_CNT))[gid] = 0u;
}

// ---------------------------------------------------------------------------
// Persistent solver: 512 WGs x 512 threads, 2 WGs per CU.
// launch_bounds(512,4): min 4 waves/EU -> VGPR cap 128.
// asm clobber v127: forces .vgpr_count >= 128, making the 64-VGPR/8-wave
// allocation tier unreachable -- r5/r6 showed the allocator otherwise picks
// 64 VGPR + scratch spill (WRITE_SIZE 4800 KB) even when the grid caps
// occupancy at 4 waves/EU.
// ---------------------------------------------------------------------------
__global__ __launch_bounds__(NTHR, 4)
void solver(const float* __restrict__ x0, const float* __restrict__ t_arr,
            const float* __restrict__ W4g, float* __restrict__ ws,
            float* __restrict__ out)
{
  asm volatile("" ::: "v127");   // pin allocation tier to 128 VGPRs

  const int tid  = threadIdx.x;
  const int wg   = blockIdx.x;
  const int lane = tid & 63;
  const int wv   = tid >> 6;
  const int nl   = lane & 15;      // MFMA fragment index
  const int g    = lane >> 4;      // k-group

  __shared__ __align__(16) u16 Ahi[2][MT][LD];
  __shared__ __align__(16) u16 Alo[2][MT][LD];
  __shared__ __align__(16) float Wsm[644];
  __shared__ __align__(16) float kS[7][MT][2];
  __shared__ __align__(16) float yL[MT][2];
  __shared__ __align__(16) float y5L[MT][2];
  __shared__ __align__(16) float pD[8][MT][2];
  __shared__ float red[8];

  // ---- one-time setup ----
  {
    const float* wp = ws + OFF_WPACK/4;
    Wsm[tid] = wp[tid];
    if (tid < 132) Wsm[512 + tid] = wp[512 + tid];
  }
  if (tid < 32) yL[tid >> 1][tid & 1] = x0[wg*32 + tid];

  // resident W2/W3 fragments (A-operand: row n = lane&15, k = g*8+e)
  const u16* w2th = (const u16*)((const char*)ws + OFF_W2TH);
  const u16* w2tl = (const u16*)((const char*)ws + OFF_W2TL);
  const u16* w3th = (const u16*)((const char*)ws + OFF_W3TH);
  const u16* w3tl = (const u16*)((const char*)ws + OFF_W3TL);
  short8 W2H[4], W2L[4], W3H[4], W3L[4];
  {
    const int nglob = wv*16 + nl;
#pragma unroll
    for (int ks = 0; ks < 4; ++ks) {
      int off = nglob*HID + ks*32 + g*8;
      W2H[ks] = *(const short8*)(w2th + off);
      W2L[ks] = *(const short8*)(w2tl + off);
      W3H[ks] = *(const short8*)(w3th + off);
      W3L[ks] = *(const short8*)(w3tl + off);
    }
  }
  // per-lane W4 slice: w4c[r][c] = W4[wv*16+g*4+r][c]
  float w4c[4][2];
#pragma unroll
  for (int r = 0; r < 4; ++r) {
    int n = wv*16 + g*4 + r;
    w4c[r][0] = W4g[n*2 + 0];
    w4c[r][1] = W4g[n*2 + 1];
  }
  __syncthreads();
  const f32x4 bv2 = *(const f32x4*)&Wsm[384 + wv*16 + g*4];
  const f32x4 bv3 = *(const f32x4*)&Wsm[512 + wv*16 + g*4];

  float* part = ws + OFF_PART/4;
  u32*  cnt   = (u32*)((char*)ws + OFF_CNT);

  float h = 0.5f * (t_arr[1] - t_arr[0]);
  float heff = h;

  // ---- phase A: inline stage combine (from pD) + L1 ----
  auto phaseA = [&](auto SC, int fromPD) {
    constexpr int S = decltype(SC)::v;
    const int m  = tid >> 5;        // 16 rows
    const int jc = tid & 31;        // 32 col-chunks of 4
    float ys0, ys1;
    const float y0 = yL[m][0], y1 = yL[m][1];
    if constexpr (S == 1) {
      ys0 = y0; ys1 = y1;
    } else {
      float kp0, kp1;
      if (S == 2 && !fromPD) {
        kp0 = kS[0][m][0]; kp1 = kS[0][m][1];
      } else {
        kp0 = Wsm[640]; kp1 = Wsm[641];
#pragma unroll
        for (int w = 0; w < 8; ++w) {
          f32x2 p = *(const f32x2*)&pD[w][m][0];
          kp0 += p[0]; kp1 += p[1];
        }
        if (jc < 2) kS[S-2][m][jc] = jc ? kp1 : kp0;
      }
      if constexpr (S == 2) {
        ys0 = fmaf(heff, CA21*kp0, y0);
        ys1 = fmaf(heff, CA21*kp1, y1);
      } else if constexpr (S == 3) {
        f32x2 k1 = *(const f32x2*)&kS[0][m][0];
        ys0 = fmaf(heff, CA31*k1[0] + CA32*kp0, y0);
        ys1 = fmaf(heff, CA31*k1[1] + CA32*kp1, y1);
      } else if constexpr (S == 4) {
        f32x2 k1 = *(const f32x2*)&kS[0][m][0];
        f32x2 k2 = *(const f32x2*)&kS[1][m][0];
        ys0 = fmaf(heff, CA41*k1[0] + CA42*k2[0] + CA43*kp0, y0);
        ys1 = fmaf(heff, CA41*k1[1] + CA42*k2[1] + CA43*kp1, y1);
      } else if constexpr (S == 5) {
        f32x2 k1 = *(const f32x2*)&kS[0][m][0];
        f32x2 k2 = *(const f32x2*)&kS[1][m][0];
        f32x2 k3 = *(const f32x2*)&kS[2][m][0];
        ys0 = fmaf(heff, CA51*k1[0] + CA52*k2[0] + CA53*k3[0] + CA54*kp0, y0);
        ys1 = fmaf(heff, CA51*k1[1] + CA52*k2[1] + CA53*k3[1] + CA54*kp1, y1);
      } else if constexpr (S == 6) {
        f32x2 k1 = *(const f32x2*)&kS[0][m][0];
        f32x2 k2 = *(const f32x2*)&kS[1][m][0];
        f32x2 k3 = *(const f32x2*)&kS[2][m][0];
        f32x2 k4 = *(const f32x2*)&kS[3][m][0];
        ys0 = fmaf(heff, CA61*k1[0] + CA62*k2[0] + CA63*k3[0] + CA64*k4[0] + CA65*kp0, y0);
        ys1 = fmaf(heff, CA61*k1[1] + CA62*k2[1] + CA63*k3[1] + CA64*k4[1] + CA65*kp1, y1);
      } else {  // S == 7: y5
        f32x2 k1 = *(const f32x2*)&kS[0][m][0];
        f32x2 k3 = *(const f32x2*)&kS[2][m][0];
        f32x2 k4 = *(const f32x2*)&kS[3][m][0];
        f32x2 k5 = *(const f32x2*)&kS[4][m][0];
        ys0 = fmaf(heff, CB1*k1[0] + CB3*k3[0] + CB4*k4[0] + CB5*k5[0] + CB6*kp0, y0);
        ys1 = fmaf(heff, CB1*k1[1] + CB3*k3[1] + CB4*k4[1] + CB5*k5[1] + CB6*kp1, y1);
        if (jc < 2) y5L[m][jc] = jc ? ys1 : ys0;
      }
    }
    // L1: 4 cols per thread
    const int j0 = jc * 4;
    f32x4 w0 = *(const f32x4*)&Wsm[j0];
    f32x4 w1 = *(const f32x4*)&Wsm[128 + j0];
    f32x4 bb = *(const f32x4*)&Wsm[256 + j0];
    float v0 = eluf(fmaf(ys1, w1[0], fmaf(ys0, w0[0], bb[0])));
    float v1 = eluf(fmaf(ys1, w1[1], fmaf(ys0, w0[1], bb[1])));
    float v2 = eluf(fmaf(ys1, w1[2], fmaf(ys0, w0[2], bb[2])));
    float v3 = eluf(fmaf(ys1, w1[3], fmaf(ys0, w0[3], bb[3])));
    u32 h01 = cvtpk(v0, v1), h23 = cvtpk(v2, v3);
    float l0 = v0 - __builtin_bit_cast(float, h01 << 16);
    float l1 = v1 - __builtin_bit_cast(float, h01 & 0xffff0000u);
    float l2 = v2 - __builtin_bit_cast(float, h23 << 16);
    float l3 = v3 - __builtin_bit_cast(float, h23 & 0xffff0000u);
    u32x2 hp = {h01, h23};
    u32x2 lp = {cvtpk(l0, l1), cvtpk(l2, l3)};
    *(u32x2*)&Ahi[0][m][j0] = hp;
    *(u32x2*)&Alo[0][m][j0] = lp;
  };

  // ---- L2: plane0 -> plane1, pack epilogue ----
  auto mmL2 = [&]() {
    f32x4 a0 = bv2, a1 = {0,0,0,0}, a2 = {0,0,0,0};
    __builtin_amdgcn_s_setprio(1);
#pragma unroll
    for (int ks = 0; ks < 4; ++ks) {
      short8 bh = *(const short8*)&Ahi[0][nl][ks*32 + g*8];
      short8 bl = *(const short8*)&Alo[0][nl][ks*32 + g*8];
      a0 = __builtin_amdgcn_mfma_f32_16x16x32_bf16(W2H[ks], bh, a0, 0, 0, 0);
      a1 = __builtin_amdgcn_mfma_f32_16x16x32_bf16(W2L[ks], bh, a1, 0, 0, 0);
      a2 = __builtin_amdgcn_mfma_f32_16x16x32_bf16(W2H[ks], bl, a2, 0, 0, 0);
    }
    __builtin_amdgcn_s_setprio(0);
    float v0 = eluf(a0[0] + a1[0] + a2[0]);
    float v1 = eluf(a0[1] + a1[1] + a2[1]);
    float v2 = eluf(a0[2] + a1[2] + a2[2]);
    float v3 = eluf(a0[3] + a1[3] + a2[3]);
    u32 h01 = cvtpk(v0, v1), h23 = cvtpk(v2, v3);
    float l0 = v0 - __builtin_bit_cast(float, h01 << 16);
    float l1 = v1 - __builtin_bit_cast(float, h01 & 0xffff0000u);
    float l2 = v2 - __builtin_bit_cast(float, h23 << 16);
    float l3 = v3 - __builtin_bit_cast(float, h23 & 0xffff0000u);
    u32x2 hp = {h01, h23};
    u32x2 lp = {cvtpk(l0, l1), cvtpk(l2, l3)};
    const int n0 = wv*16 + g*4;
    *(u32x2*)&Ahi[1][nl][n0] = hp;
    *(u32x2*)&Alo[1][nl][n0] = lp;
  };

  // ---- L3 + fused L4 dot -> pD ----
  auto mmL3 = [&]() {
    f32x4 a0 = bv3, a1 = {0,0,0,0}, a2 = {0,0,0,0};
    __builtin_amdgcn_s_setprio(1);
#pragma unroll
    for (int ks = 0; ks < 4; ++ks) {
      short8 bh = *(const short8*)&Ahi[1][nl][ks*32 + g*8];
      short8 bl = *(const short8*)&Alo[1][nl][ks*32 + g*8];
      a0 = __builtin_amdgcn_mfma_f32_16x16x32_bf16(W3H[ks], bh, a0, 0, 0, 0);
      a1 = __builtin_amdgcn_mfma_f32_16x16x32_bf16(W3L[ks], bh, a1, 0, 0, 0);
      a2 = __builtin_amdgcn_mfma_f32_16x16x32_bf16(W3H[ks], bl, a2, 0, 0, 0);
    }
    __builtin_amdgcn_s_setprio(0);
    float v0 = eluf(a0[0] + a1[0] + a2[0]);
    float v1 = eluf(a0[1] + a1[1] + a2[1]);
    float v2 = eluf(a0[2] + a1[2] + a2[2]);
    float v3 = eluf(a0[3] + a1[3] + a2[3]);
    float p0 = v0*w4c[0][0] + v1*w4c[1][0] + v2*w4c[2][0] + v3*w4c[3][0];
    float p1 = v0*w4c[0][1] + v1*w4c[1][1] + v2*w4c[2][1] + v3*w4c[3][1];
    p0 += __shfl_xor(p0, 16); p0 += __shfl_xor(p0, 32);
    p1 += __shfl_xor(p1, 16); p1 += __shfl_xor(p1, 32);
    if (lane < 16) {
      f32x2 pp = {p0, p1};
      *(f32x2*)&pD[wv][lane][0] = pp;
    }
  };

  // ---- main adaptive loop ----
  for (int iv = 0; iv < 7; ++iv) {
    const float t1 = t_arr[iv + 1];
    float tc = t_arr[iv];
    for (int s = 0; s < 8; ++s) {
      const int step = iv*8 + s;
      float rem = t1 - tc;
      if (rem <= 1e-9f) break;          // uniform across all WGs
      heff = fminf(h, rem);

      if (iv == 0 && s == 0) {          // fresh k1 eval
        phaseA(IC<1>{}, 0); __syncthreads();
        mmL2(); __syncthreads();
        mmL3(); __syncthreads();
        phaseA(IC<2>{}, 1);
      } else {
        phaseA(IC<2>{}, 0);             // FSAL: k1 = kS[0]
      }
      __syncthreads(); mmL2(); __syncthreads(); mmL3(); __syncthreads();
      phaseA(IC<3>{}, 1); __syncthreads(); mmL2(); __syncthreads(); mmL3(); __syncthreads();
      phaseA(IC<4>{}, 1); __syncthreads(); mmL2(); __syncthreads(); mmL3(); __syncthreads();
      phaseA(IC<5>{}, 1); __syncthreads(); mmL2(); __syncthreads(); mmL3(); __syncthreads();
      phaseA(IC<6>{}, 1); __syncthreads(); mmL2(); __syncthreads(); mmL3(); __syncthreads();
      phaseA(IC<7>{}, 1); __syncthreads(); mmL2(); __syncthreads(); mmL3(); __syncthreads();
      // pD now holds k7 partials

      // ---- error partial (wave 0) + publish ----
      if (wv == 0 && lane < 32) {
        int m = lane >> 1, c = lane & 1;
        float kp = Wsm[640 + c];
#pragma unroll
        for (int w = 0; w < 8; ++w) kp += pD[w][m][c];
        kS[6][m][c] = kp;
        float e = heff * (CE1*kS[0][m][c] + CE3*kS[2][m][c] + CE4*kS[3][m][c]
                        + CE5*kS[4][m][c] + CE6*kS[5][m][c] + CE7*kp);
        float tol = 1e-4f + 1e-3f * fmaxf(fabsf(yL[m][c]), fabsf(y5L[m][c]));
        float rr = e / tol;
        float es = rr * rr;
#pragma unroll
        for (int mk = 1; mk < 32; mk <<= 1) es += __shfl_xor(es, mk);
        if (lane == 0) {
          __hip_atomic_store(&part[(step & 1)*NWG + wg], es, __ATOMIC_RELAXED, __HIP_MEMORY_SCOPE_AGENT);
          __hip_atomic_fetch_add(&cnt[step], 1u, __ATOMIC_RELEASE, __HIP_MEMORY_SCOPE_AGENT);
        }
      }
      if (tid == 0) {
        while (__hip_atomic_load(&cnt[step], __ATOMIC_ACQUIRE, __HIP_MEMORY_SCOPE_AGENT) < (u32)NWG)
          __builtin_amdgcn_s_sleep(2);
      }
      __syncthreads();
      // ---- symmetric deterministic reduce (every WG, fixed order) ----
      float pv = __hip_atomic_load(&part[(step & 1)*NWG + tid], __ATOMIC_RELAXED, __HIP_MEMORY_SCOPE_AGENT);
#pragma unroll
      for (int mk = 1; mk < 64; mk <<= 1) pv += __shfl_xor(pv, mk);
      if (lane == 0) red[wv] = pv;
      __syncthreads();
      float err_norm = sqrtf((red[0] + red[1] + red[2] + red[3]
                            + red[4] + red[5] + red[6] + red[7]) * (1.0f/16384.f));
      bool acc = (err_norm <= 1.0f);
      float factor = fminf(10.f, fmaxf(0.2f, 0.9f * powf(fmaxf(err_norm, 1e-10f), -0.2f)));
      if (acc) {
        if (tid < 32) { int m = tid >> 1, c = tid & 1;
          yL[m][c] = y5L[m][c];
          kS[0][m][c] = kS[6][m][c];     // FSAL: k1 <- k7
        }
        tc += heff;
      }
      h = heff * factor;
      __syncthreads();
    }
    if (tid < 32)
      out[(size_t)(iv + 1) * 16384 + wg*32 + tid] = yL[tid >> 1][tid & 1];
  }
}

extern "C" void kernel_launch(void* const* d_in, const int* in_sizes, int n_in,
                              void* d_out, int out_size, void* d_ws, size_t ws_size,
                              hipStream_t stream)
{
  const float* x0 = (const float*)d_in[0];
  const float* t  = (const float*)d_in[1];
  const float* W1 = (const float*)d_in[2];
  const float* b1 = (const float*)d_in[3];
  const float* W2 = (const float*)d_in[4];
  const float* b2 = (const float*)d_in[5];
  const float* W3 = (const float*)d_in[6];
  const float* b3 = (const float*)d_in[7];
  const float* W4 = (const float*)d_in[8];
  const float* b4 = (const float*)d_in[9];
  float* out = (float*)d_out;
  float* ws  = (float*)d_ws;

  prologue<<<64, 256, 0, stream>>>(x0, t, W1, b1, W2, b2, W3, b3, W4, b4, ws, out);
  solver<<<NWG, NTHR, 0, stream>>>(x0, t, W4, ws, out);
}

// Round 9
// 256.461 us; speedup vs baseline: 1.7298x; 1.6721x over previous
//
#include <hip/hip_runtime.h>
#include <stdint.h>

typedef unsigned int u32;
typedef unsigned short u16;
typedef float f32x4 __attribute__((ext_vector_type(4)));
typedef float f32x2 __attribute__((ext_vector_type(2)));
typedef short short8 __attribute__((ext_vector_type(8)));
typedef unsigned int u32x2 __attribute__((ext_vector_type(2)));
typedef unsigned int u32x4 __attribute__((ext_vector_type(4)));

#define HID  128
#define MT   32        // batch rows per WG
#define NWG  256       // 8192/32, 1 WG per CU -> co-resident by construction
#define NTHR 512       // 8 waves
#define LD   136       // LDS plane stride in u16 (272B rows)

// ---- ws byte offsets ----
#define OFF_PART  0        // 2 x 256 f32 (parity double-buffered)
#define OFF_LEAF  2048     // 56 x 16 u32 arrival tree leaves
#define OFF_ROOT  5632     // 56 u32 roots
#define OFF_FLAG  5888     // 56 u32 accept/ready flags
#define OFF_HPAY  6144     // 56 f32 next-h payload
#define OFF_WPACK 8192     // 644 f32: W1(256) b1(128) b2(128) b3(128) b4(2)
#define OFF_W2TH  16384    // 128x128 bf16 [n][k] hi
#define OFF_W2TL  49152
#define OFF_W3TH  81920
#define OFF_W3TL  114688

constexpr float CA21 = (float)(1.0/5.0);
constexpr float CA31 = (float)(3.0/40.0),   CA32 = (float)(9.0/40.0);
constexpr float CA41 = (float)(44.0/45.0),  CA42 = (float)(-56.0/15.0), CA43 = (float)(32.0/9.0);
constexpr float CA51 = (float)(19372.0/6561.0), CA52 = (float)(-25360.0/2187.0);
constexpr float CA53 = (float)(64448.0/6561.0), CA54 = (float)(-212.0/729.0);
constexpr float CA61 = (float)(9017.0/3168.0),  CA62 = (float)(-355.0/33.0);
constexpr float CA63 = (float)(46732.0/5247.0), CA64 = (float)(49.0/176.0), CA65 = (float)(-5103.0/18656.0);
constexpr float CB1 = (float)(35.0/384.0), CB3 = (float)(500.0/1113.0), CB4 = (float)(125.0/192.0);
constexpr float CB5 = (float)(-2187.0/6784.0), CB6 = (float)(11.0/84.0);
constexpr float CE1 = (float)(35.0/384.0 - 5179.0/57600.0);
constexpr float CE3 = (float)(500.0/1113.0 - 7571.0/16695.0);
constexpr float CE4 = (float)(125.0/192.0 - 393.0/640.0);
constexpr float CE5 = (float)(-2187.0/6784.0 + 92097.0/339200.0);
constexpr float CE6 = (float)(11.0/84.0 - 187.0/2100.0);
constexpr float CE7 = (float)(-1.0/40.0);

template<int N> struct IC { static constexpr int v = N; };

__device__ __forceinline__ u16 f2bf(float x) {
  u32 u = __builtin_bit_cast(u32, x);
  u32 r = (u + 0x7FFFu + ((u >> 16) & 1u)) >> 16;
  return (u16)r;
}
__device__ __forceinline__ float bf2f(u16 b) {
  u32 u = ((u32)b) << 16;
  return __builtin_bit_cast(float, u);
}
__device__ __forceinline__ float eluf(float x) {
  return x > 0.f ? x : (__expf(x) - 1.f);
}
// v_cvt_pk_bf16_f32: dst[15:0]=bf16(a), dst[31:16]=bf16(b) (RNE)
__device__ __forceinline__ u32 cvtpk(float a, float b) {
  u32 r; asm("v_cvt_pk_bf16_f32 %0, %1, %2" : "=v"(r) : "v"(a), "v"(b)); return r;
}

// ---------------------------------------------------------------------------
// Prologue
// ---------------------------------------------------------------------------
__global__ void prologue(const float* __restrict__ x0, const float* __restrict__ t,
                         const float* __restrict__ W1, const float* __restrict__ b1,
                         const float* __restrict__ W2, const float* __restrict__ b2,
                         const float* __restrict__ W3, const float* __restrict__ b3,
                         const float* __restrict__ W4, const float* __restrict__ b4,
                         float* __restrict__ ws, float* __restrict__ out)
{
  int gid = blockIdx.x * blockDim.x + threadIdx.x;   // 64*256 = 16384
  out[gid] = x0[gid];
  {
    int k = gid >> 7, j = gid & 127;
    u16* w2th = (u16*)((char*)ws + OFF_W2TH);
    u16* w2tl = (u16*)((char*)ws + OFF_W2TL);
    u16* w3th = (u16*)((char*)ws + OFF_W3TH);
    u16* w3tl = (u16*)((char*)ws + OFF_W3TL);
    float w = W2[gid];
    u16 hb = f2bf(w);
    w2th[j*HID + k] = hb;
    w2tl[j*HID + k] = f2bf(w - bf2f(hb));
    w = W3[gid];
    hb = f2bf(w);
    w3th[j*HID + k] = hb;
    w3tl[j*HID + k] = f2bf(w - bf2f(hb));
  }
  float* wp = ws + OFF_WPACK/4;
  if (gid < 256) wp[gid] = W1[gid];
  if (gid < 128) {
    wp[256 + gid] = b1[gid];
    wp[384 + gid] = b2[gid];
    wp[512 + gid] = b3[gid];
  }
  if (gid < 2)  wp[640 + gid] = b4[gid];
  if (gid < 1600) ((u32*)ws)[gid] = 0u;   // part/leaf/root/flag/hpay zeroed
}

// ---------------------------------------------------------------------------
// Persistent solver: 256 WGs x 512 threads, 1 WG/CU (deadlock-proof).
// Activations: single bf16 (RNE). Weights: bf16 hi+lo -> 2 MFMAs per tile.
// Controller: 16-way tree arrival + WG0 reduce + flag broadcast.
// ---------------------------------------------------------------------------
__global__ __launch_bounds__(NTHR, 2)
void solver(const float* __restrict__ x0, const float* __restrict__ t_arr,
            const float* __restrict__ W4g, float* __restrict__ ws,
            float* __restrict__ out)
{
  const int tid  = threadIdx.x;
  const int wg   = blockIdx.x;
  const int lane = tid & 63;
  const int wv   = tid >> 6;
  const int nl   = lane & 15;      // MFMA fragment index (batch-row within tile)
  const int g    = lane >> 4;      // k-group

  __shared__ __align__(16) u16 Ahi[2][MT][LD];
  __shared__ __align__(16) float Wsm[644];
  __shared__ __align__(16) float kS[7][MT][2];
  __shared__ __align__(16) float yL[MT][2];
  __shared__ __align__(16) float y5L[MT][2];
  __shared__ __align__(16) float pD[8][2][16][2];
  __shared__ float red[8];
  __shared__ u32 bcF;
  __shared__ float bcH;

  // ---- one-time setup ----
  {
    const float* wp = ws + OFF_WPACK/4;
    Wsm[tid] = wp[tid];
    if (tid < 132) Wsm[512 + tid] = wp[512 + tid];
  }
  if (tid < 64) yL[tid >> 1][tid & 1] = x0[wg*64 + tid];

  // resident W2/W3 fragments (A-operand: row n = wv*16 + nl, k = ks*32+g*8)
  const u16* w2th = (const u16*)((const char*)ws + OFF_W2TH);
  const u16* w2tl = (const u16*)((const char*)ws + OFF_W2TL);
  const u16* w3th = (const u16*)((const char*)ws + OFF_W3TH);
  const u16* w3tl = (const u16*)((const char*)ws + OFF_W3TL);
  short8 W2H[4], W2L[4], W3H[4], W3L[4];
  {
    const int nglob = wv*16 + nl;
#pragma unroll
    for (int ks = 0; ks < 4; ++ks) {
      int off = nglob*HID + ks*32 + g*8;
      W2H[ks] = *(const short8*)(w2th + off);
      W2L[ks] = *(const short8*)(w2tl + off);
      W3H[ks] = *(const short8*)(w3th + off);
      W3L[ks] = *(const short8*)(w3tl + off);
    }
  }
  // per-lane W4 slice: w4c[r][c] = W4[wv*16+g*4+r][c]
  float w4c[4][2];
#pragma unroll
  for (int r = 0; r < 4; ++r) {
    int n = wv*16 + g*4 + r;
    w4c[r][0] = W4g[n*2 + 0];
    w4c[r][1] = W4g[n*2 + 1];
  }
  __syncthreads();
  const f32x4 bv2 = *(const f32x4*)&Wsm[384 + wv*16 + g*4];
  const f32x4 bv3 = *(const f32x4*)&Wsm[512 + wv*16 + g*4];

  float* part = ws + OFF_PART/4;
  u32*  leaf  = (u32*)((char*)ws + OFF_LEAF);
  u32*  root  = (u32*)((char*)ws + OFF_ROOT);
  u32*  flg   = (u32*)((char*)ws + OFF_FLAG);
  float* hpay = (float*)((char*)ws + OFF_HPAY);

  float h = 0.5f * (t_arr[1] - t_arr[0]);
  float heff = h;

  // ---- phase A: inline stage combine (from pD) + L1 ----
  auto phaseA = [&](auto SC, int fromPD) {
    constexpr int S = decltype(SC)::v;
    const int m  = tid >> 4;        // 32 rows
    const int jc = tid & 15;        // 16 col-chunks of 8
    float ys0, ys1;
    const float y0 = yL[m][0], y1 = yL[m][1];
    if constexpr (S == 1) {
      ys0 = y0; ys1 = y1;
    } else {
      const int mt = m >> 4, ml = m & 15;
      float kp0, kp1;
      if (S == 2 && !fromPD) {
        kp0 = kS[0][m][0]; kp1 = kS[0][m][1];
      } else {
        kp0 = Wsm[640]; kp1 = Wsm[641];
#pragma unroll
        for (int w = 0; w < 8; ++w) {
          f32x2 p = *(const f32x2*)&pD[w][mt][ml][0];
          kp0 += p[0]; kp1 += p[1];
        }
        if (jc < 2) kS[S-2][m][jc] = jc ? kp1 : kp0;
      }
      if constexpr (S == 2) {
        ys0 = fmaf(heff, CA21*kp0, y0);
        ys1 = fmaf(heff, CA21*kp1, y1);
      } else if constexpr (S == 3) {
        f32x2 k1 = *(const f32x2*)&kS[0][m][0];
        ys0 = fmaf(heff, CA31*k1[0] + CA32*kp0, y0);
        ys1 = fmaf(heff, CA31*k1[1] + CA32*kp1, y1);
      } else if constexpr (S == 4) {
        f32x2 k1 = *(const f32x2*)&kS[0][m][0];
        f32x2 k2 = *(const f32x2*)&kS[1][m][0];
        ys0 = fmaf(heff, CA41*k1[0] + CA42*k2[0] + CA43*kp0, y0);
        ys1 = fmaf(heff, CA41*k1[1] + CA42*k2[1] + CA43*kp1, y1);
      } else if constexpr (S == 5) {
        f32x2 k1 = *(const f32x2*)&kS[0][m][0];
        f32x2 k2 = *(const f32x2*)&kS[1][m][0];
        f32x2 k3 = *(const f32x2*)&kS[2][m][0];
        ys0 = fmaf(heff, CA51*k1[0] + CA52*k2[0] + CA53*k3[0] + CA54*kp0, y0);
        ys1 = fmaf(heff, CA51*k1[1] + CA52*k2[1] + CA53*k3[1] + CA54*kp1, y1);
      } else if constexpr (S == 6) {
        f32x2 k1 = *(const f32x2*)&kS[0][m][0];
        f32x2 k2 = *(const f32x2*)&kS[1][m][0];
        f32x2 k3 = *(const f32x2*)&kS[2][m][0];
        f32x2 k4 = *(const f32x2*)&kS[3][m][0];
        ys0 = fmaf(heff, CA61*k1[0] + CA62*k2[0] + CA63*k3[0] + CA64*k4[0] + CA65*kp0, y0);
        ys1 = fmaf(heff, CA61*k1[1] + CA62*k2[1] + CA63*k3[1] + CA64*k4[1] + CA65*kp1, y1);
      } else {  // S == 7: y5
        f32x2 k1 = *(const f32x2*)&kS[0][m][0];
        f32x2 k3 = *(const f32x2*)&kS[2][m][0];
        f32x2 k4 = *(const f32x2*)&kS[3][m][0];
        f32x2 k5 = *(const f32x2*)&kS[4][m][0];
        ys0 = fmaf(heff, CB1*k1[0] + CB3*k3[0] + CB4*k4[0] + CB5*k5[0] + CB6*kp0, y0);
        ys1 = fmaf(heff, CB1*k1[1] + CB3*k3[1] + CB4*k4[1] + CB5*k5[1] + CB6*kp1, y1);
        if (jc < 2) y5L[m][jc] = jc ? ys1 : ys0;
      }
    }
    // L1: 8 cols per thread, single-bf16 pack
    const int j0 = jc * 8;
    f32x4 w0a = *(const f32x4*)&Wsm[j0],       w0b = *(const f32x4*)&Wsm[j0 + 4];
    f32x4 w1a = *(const f32x4*)&Wsm[128 + j0], w1b = *(const f32x4*)&Wsm[128 + j0 + 4];
    f32x4 ba  = *(const f32x4*)&Wsm[256 + j0], bb  = *(const f32x4*)&Wsm[256 + j0 + 4];
    float v0 = eluf(fmaf(ys1, w1a[0], fmaf(ys0, w0a[0], ba[0])));
    float v1 = eluf(fmaf(ys1, w1a[1], fmaf(ys0, w0a[1], ba[1])));
    float v2 = eluf(fmaf(ys1, w1a[2], fmaf(ys0, w0a[2], ba[2])));
    float v3 = eluf(fmaf(ys1, w1a[3], fmaf(ys0, w0a[3], ba[3])));
    float v4 = eluf(fmaf(ys1, w1b[0], fmaf(ys0, w0b[0], bb[0])));
    float v5 = eluf(fmaf(ys1, w1b[1], fmaf(ys0, w0b[1], bb[1])));
    float v6 = eluf(fmaf(ys1, w1b[2], fmaf(ys0, w0b[2], bb[2])));
    float v7 = eluf(fmaf(ys1, w1b[3], fmaf(ys0, w0b[3], bb[3])));
    u32x4 hp = {cvtpk(v0,v1), cvtpk(v2,v3), cvtpk(v4,v5), cvtpk(v6,v7)};
    *(u32x4*)&Ahi[0][m][j0] = hp;
  };

  // ---- L2: plane0 -> plane1 (2 MFMAs/tile: W-hi, W-lo) ----
  auto mmL2 = [&]() {
    f32x4 a0[2], a1[2];
    a0[0] = bv2; a0[1] = bv2; a1[0] = {0,0,0,0}; a1[1] = {0,0,0,0};
    __builtin_amdgcn_s_setprio(1);
#pragma unroll
    for (int ks = 0; ks < 4; ++ks)
#pragma unroll
      for (int mt = 0; mt < 2; ++mt) {
        short8 bh = *(const short8*)&Ahi[0][mt*16 + nl][ks*32 + g*8];
        a0[mt] = __builtin_amdgcn_mfma_f32_16x16x32_bf16(W2H[ks], bh, a0[mt], 0, 0, 0);
        a1[mt] = __builtin_amdgcn_mfma_f32_16x16x32_bf16(W2L[ks], bh, a1[mt], 0, 0, 0);
      }
    __builtin_amdgcn_s_setprio(0);
    const int n0 = wv*16 + g*4;
#pragma unroll
    for (int mt = 0; mt < 2; ++mt) {
      float v0 = eluf(a0[mt][0] + a1[mt][0]);
      float v1 = eluf(a0[mt][1] + a1[mt][1]);
      float v2 = eluf(a0[mt][2] + a1[mt][2]);
      float v3 = eluf(a0[mt][3] + a1[mt][3]);
      u32x2 hp = {cvtpk(v0, v1), cvtpk(v2, v3)};
      *(u32x2*)&Ahi[1][mt*16 + nl][n0] = hp;
    }
  };

  // ---- L3 + fused L4 dot -> pD ----
  auto mmL3 = [&]() {
    f32x4 a0[2], a1[2];
    a0[0] = bv3; a0[1] = bv3; a1[0] = {0,0,0,0}; a1[1] = {0,0,0,0};
    __builtin_amdgcn_s_setprio(1);
#pragma unroll
    for (int ks = 0; ks < 4; ++ks)
#pragma unroll
      for (int mt = 0; mt < 2; ++mt) {
        short8 bh = *(const short8*)&Ahi[1][mt*16 + nl][ks*32 + g*8];
        a0[mt] = __builtin_amdgcn_mfma_f32_16x16x32_bf16(W3H[ks], bh, a0[mt], 0, 0, 0);
        a1[mt] = __builtin_amdgcn_mfma_f32_16x16x32_bf16(W3L[ks], bh, a1[mt], 0, 0, 0);
      }
    __builtin_amdgcn_s_setprio(0);
#pragma unroll
    for (int mt = 0; mt < 2; ++mt) {
      float v0 = a0[mt][0] + a1[mt][0];
      float v1 = a0[mt][1] + a1[mt][1];
      float v2 = a0[mt][2] + a1[mt][2];
      float v3 = a0[mt][3] + a1[mt][3];
      v0 = eluf(v0); v1 = eluf(v1); v2 = eluf(v2); v3 = eluf(v3);
      float p0 = v0*w4c[0][0] + v1*w4c[1][0] + v2*w4c[2][0] + v3*w4c[3][0];
      float p1 = v0*w4c[0][1] + v1*w4c[1][1] + v2*w4c[2][1] + v3*w4c[3][1];
      p0 += __shfl_xor(p0, 16); p0 += __shfl_xor(p0, 32);
      p1 += __shfl_xor(p1, 16); p1 += __shfl_xor(p1, 32);
      if (lane < 16) {
        f32x2 pp = {p0, p1};
        *(f32x2*)&pD[wv][mt][lane][0] = pp;
      }
    }
  };

  // ---- main adaptive loop ----
  for (int iv = 0; iv < 7; ++iv) {
    const float t1 = t_arr[iv + 1];
    float tc = t_arr[iv];
    for (int s = 0; s < 8; ++s) {
      const int step = iv*8 + s;
      float rem = t1 - tc;
      if (rem <= 1e-9f) break;          // uniform across all WGs
      heff = fminf(h, rem);

      if (iv == 0 && s == 0) {          // fresh k1 eval
        phaseA(IC<1>{}, 0); __syncthreads();
        mmL2(); __syncthreads();
        mmL3(); __syncthreads();
        phaseA(IC<2>{}, 1);
      } else {
        phaseA(IC<2>{}, 0);             // FSAL: k1 = kS[0]
      }
      __syncthreads(); mmL2(); __syncthreads(); mmL3(); __syncthreads();
      phaseA(IC<3>{}, 1); __syncthreads(); mmL2(); __syncthreads(); mmL3(); __syncthreads();
      phaseA(IC<4>{}, 1); __syncthreads(); mmL2(); __syncthreads(); mmL3(); __syncthreads();
      phaseA(IC<5>{}, 1); __syncthreads(); mmL2(); __syncthreads(); mmL3(); __syncthreads();
      phaseA(IC<6>{}, 1); __syncthreads(); mmL2(); __syncthreads(); mmL3(); __syncthreads();
      phaseA(IC<7>{}, 1); __syncthreads(); mmL2(); __syncthreads(); mmL3(); __syncthreads();
      // pD now holds k7 partials

      // ---- error partial (wave 0) + tree arrival ----
      if (wv == 0) {
        int m = lane >> 1, c = lane & 1;
        int emt = m >> 4, eml = m & 15;
        float kp = Wsm[640 + c];
#pragma unroll
        for (int w = 0; w < 8; ++w) kp += pD[w][emt][eml][c];
        kS[6][m][c] = kp;
        float e = heff * (CE1*kS[0][m][c] + CE3*kS[2][m][c] + CE4*kS[3][m][c]
                        + CE5*kS[4][m][c] + CE6*kS[5][m][c] + CE7*kp);
        float tol = 1e-4f + 1e-3f * fmaxf(fabsf(yL[m][c]), fabsf(y5L[m][c]));
        float rr = e / tol;
        float es = rr * rr;
#pragma unroll
        for (int mk = 1; mk < 64; mk <<= 1) es += __shfl_xor(es, mk);
        if (lane == 0) {
          __hip_atomic_store(&part[(step & 1)*NWG + wg], es, __ATOMIC_RELAXED, __HIP_MEMORY_SCOPE_AGENT);
          u32 old = __hip_atomic_fetch_add(&leaf[step*16 + (wg >> 4)], 1u, __ATOMIC_ACQ_REL, __HIP_MEMORY_SCOPE_AGENT);
          if (old == 15u)
            __hip_atomic_fetch_add(&root[step], 1u, __ATOMIC_ACQ_REL, __HIP_MEMORY_SCOPE_AGENT);
        }
      }
      // ---- WG0: global reduce + publish ----
      if (wg == 0) {
        if (tid == 0) {
          while (__hip_atomic_load(&root[step], __ATOMIC_ACQUIRE, __HIP_MEMORY_SCOPE_AGENT) < 16u)
            __builtin_amdgcn_s_sleep(2);
        }
        __syncthreads();
        float pv = 0.f;
        if (tid < NWG)
          pv = __hip_atomic_load(&part[(step & 1)*NWG + tid], __ATOMIC_RELAXED, __HIP_MEMORY_SCOPE_AGENT);
#pragma unroll
        for (int mk = 1; mk < 64; mk <<= 1) pv += __shfl_xor(pv, mk);
        if (lane == 0) red[wv] = pv;
        __syncthreads();
        if (tid == 0) {
          float err_norm = sqrtf((red[0] + red[1] + red[2] + red[3]) * (1.0f/16384.f));
          bool acc = (err_norm <= 1.0f);
          float factor = fminf(10.f, fmaxf(0.2f, 0.9f * powf(fmaxf(err_norm, 1e-10f), -0.2f)));
          __hip_atomic_store(&hpay[step], heff * factor, __ATOMIC_RELAXED, __HIP_MEMORY_SCOPE_AGENT);
          __hip_atomic_store(&flg[step], acc ? 3u : 1u, __ATOMIC_RELEASE, __HIP_MEMORY_SCOPE_AGENT);
        }
      }
      // ---- all WGs: wait for decision ----
      if (tid == 0) {
        u32 f;
        while (((f = __hip_atomic_load(&flg[step], __ATOMIC_ACQUIRE, __HIP_MEMORY_SCOPE_AGENT)) & 1u) == 0u)
          __builtin_amdgcn_s_sleep(2);
        bcF = f;
        bcH = __hip_atomic_load(&hpay[step], __ATOMIC_RELAXED, __HIP_MEMORY_SCOPE_AGENT);
      }
      __syncthreads();
      {
        bool acc = (bcF & 2u) != 0u;
        if (acc) {
          if (tid < 64) { int m = tid >> 1, c = tid & 1;
            yL[m][c] = y5L[m][c];
            kS[0][m][c] = kS[6][m][c];   // FSAL: k1 <- k7
          }
          tc += heff;
        }
        h = bcH;
      }
      __syncthreads();
    }
    if (tid < 64)
      out[(size_t)(iv + 1) * 16384 + wg*64 + tid] = yL[tid >> 1][tid & 1];
  }
}

extern "C" void kernel_launch(void* const* d_in, const int* in_sizes, int n_in,
                              void* d_out, int out_size, void* d_ws, size_t ws_size,
                              hipStream_t stream)
{
  const float* x0 = (const float*)d_in[0];
  const float* t  = (const float*)d_in[1];
  const float* W1 = (const float*)d_in[2];
  const float* b1 = (const float*)d_in[3];
  const float* W2 = (const float*)d_in[4];
  const float* b2 = (const float*)d_in[5];
  const float* W3 = (const float*)d_in[6];
  const float* b3 = (const float*)d_in[7];
  const float* W4 = (const float*)d_in[8];
  const float* b4 = (const float*)d_in[9];
  float* out = (float*)d_out;
  float* ws  = (float*)d_ws;

  prologue<<<64, 256, 0, stream>>>(x0, t, W1, b1, W2, b2, W3, b3, W4, b4, ws, out);
  solver<<<NWG, NTHR, 0, stream>>>(x0, t, W4, ws, out);
}

// Round 10
// 205.805 us; speedup vs baseline: 2.1556x; 1.2461x over previous
//
#include <hip/hip_runtime.h>
#include <stdint.h>

typedef unsigned int u32;
typedef unsigned long long u64;
typedef unsigned short u16;
typedef float f32x4 __attribute__((ext_vector_type(4)));
typedef float f32x2 __attribute__((ext_vector_type(2)));
typedef short short8 __attribute__((ext_vector_type(8)));
typedef unsigned int u32x2 __attribute__((ext_vector_type(2)));
typedef unsigned int u32x4 __attribute__((ext_vector_type(4)));

#define HID  128
#define MT   32        // batch rows per WG
#define NWG  256       // 8192/32, 1 WG per CU -> co-resident by construction
#define NTHR 512       // 8 waves
#define LD   136       // LDS plane stride in u16 (272B rows)

// ---- ws byte offsets ----
#define OFF_ESUM  0        // 56 u64 fixed-point error sums (x 2^20)
#define OFF_CNT   512      // 56 u32 arrival counters
#define OFF_WPACK 8192     // 644 f32: W1(256) b1(128) b2(128) b3(128) b4(2)
#define OFF_W2TH  16384    // 128x128 bf16 [n][k] hi
#define OFF_W2TL  49152
#define OFF_W3TH  81920
#define OFF_W3TL  114688

constexpr float CA21 = (float)(1.0/5.0);
constexpr float CA31 = (float)(3.0/40.0),   CA32 = (float)(9.0/40.0);
constexpr float CA41 = (float)(44.0/45.0),  CA42 = (float)(-56.0/15.0), CA43 = (float)(32.0/9.0);
constexpr float CA51 = (float)(19372.0/6561.0), CA52 = (float)(-25360.0/2187.0);
constexpr float CA53 = (float)(64448.0/6561.0), CA54 = (float)(-212.0/729.0);
constexpr float CA61 = (float)(9017.0/3168.0),  CA62 = (float)(-355.0/33.0);
constexpr float CA63 = (float)(46732.0/5247.0), CA64 = (float)(49.0/176.0), CA65 = (float)(-5103.0/18656.0);
constexpr float CB1 = (float)(35.0/384.0), CB3 = (float)(500.0/1113.0), CB4 = (float)(125.0/192.0);
constexpr float CB5 = (float)(-2187.0/6784.0), CB6 = (float)(11.0/84.0);
constexpr float CE1 = (float)(35.0/384.0 - 5179.0/57600.0);
constexpr float CE3 = (float)(500.0/1113.0 - 7571.0/16695.0);
constexpr float CE4 = (float)(125.0/192.0 - 393.0/640.0);
constexpr float CE5 = (float)(-2187.0/6784.0 + 92097.0/339200.0);
constexpr float CE6 = (float)(11.0/84.0 - 187.0/2100.0);
constexpr float CE7 = (float)(-1.0/40.0);

template<int N> struct IC { static constexpr int v = N; };

__device__ __forceinline__ u16 f2bf(float x) {
  u32 u = __builtin_bit_cast(u32, x);
  u32 r = (u + 0x7FFFu + ((u >> 16) & 1u)) >> 16;
  return (u16)r;
}
__device__ __forceinline__ float bf2f(u16 b) {
  u32 u = ((u32)b) << 16;
  return __builtin_bit_cast(float, u);
}
__device__ __forceinline__ float eluf(float x) {
  return x > 0.f ? x : (__expf(x) - 1.f);
}
// v_cvt_pk_bf16_f32: dst[15:0]=bf16(a), dst[31:16]=bf16(b) (RNE)
__device__ __forceinline__ u32 cvtpk(float a, float b) {
  u32 r; asm("v_cvt_pk_bf16_f32 %0, %1, %2" : "=v"(r) : "v"(a), "v"(b)); return r;
}

// ---------------------------------------------------------------------------
// Prologue
// ---------------------------------------------------------------------------
__global__ void prologue(const float* __restrict__ x0, const float* __restrict__ t,
                         const float* __restrict__ W1, const float* __restrict__ b1,
                         const float* __restrict__ W2, const float* __restrict__ b2,
                         const float* __restrict__ W3, const float* __restrict__ b3,
                         const float* __restrict__ W4, const float* __restrict__ b4,
                         float* __restrict__ ws, float* __restrict__ out)
{
  int gid = blockIdx.x * blockDim.x + threadIdx.x;   // 64*256 = 16384
  out[gid] = x0[gid];
  {
    int k = gid >> 7, j = gid & 127;
    u16* w2th = (u16*)((char*)ws + OFF_W2TH);
    u16* w2tl = (u16*)((char*)ws + OFF_W2TL);
    u16* w3th = (u16*)((char*)ws + OFF_W3TH);
    u16* w3tl = (u16*)((char*)ws + OFF_W3TL);
    float w = W2[gid];
    u16 hb = f2bf(w);
    w2th[j*HID + k] = hb;
    w2tl[j*HID + k] = f2bf(w - bf2f(hb));
    w = W3[gid];
    hb = f2bf(w);
    w3th[j*HID + k] = hb;
    w3tl[j*HID + k] = f2bf(w - bf2f(hb));
  }
  float* wp = ws + OFF_WPACK/4;
  if (gid < 256) wp[gid] = W1[gid];
  if (gid < 128) {
    wp[256 + gid] = b1[gid];
    wp[384 + gid] = b2[gid];
    wp[512 + gid] = b3[gid];
  }
  if (gid < 2)  wp[640 + gid] = b4[gid];
  if (gid < 256) ((u32*)ws)[gid] = 0u;   // esum64[56] + cnt[56] zeroed
}

// ---------------------------------------------------------------------------
// Persistent solver: 256 WGs x 512 threads, 1 WG/CU (deadlock-proof).
// Activations: single bf16 (RNE). Weights: bf16 hi+lo -> 2 MFMAs per tile.
// Controller: single deterministic fixed-point u64 atomic sum + release
// counter; every WG polls and computes the decision locally (no WG0 hop,
// no part[] reduce -- r9's centralized chain cost ~1 us/substep extra).
// ---------------------------------------------------------------------------
__global__ __launch_bounds__(NTHR, 2)
void solver(const float* __restrict__ x0, const float* __restrict__ t_arr,
            const float* __restrict__ W4g, float* __restrict__ ws,
            float* __restrict__ out)
{
  const int tid  = threadIdx.x;
  const int wg   = blockIdx.x;
  const int lane = tid & 63;
  const int wv   = tid >> 6;
  const int nl   = lane & 15;      // MFMA fragment index (batch-row within tile)
  const int g    = lane >> 4;      // k-group

  __shared__ __align__(16) u16 Ahi[2][MT][LD];
  __shared__ __align__(16) float Wsm[644];
  __shared__ __align__(16) float kS[7][MT][2];
  __shared__ __align__(16) float yL[MT][2];
  __shared__ __align__(16) float y5L[MT][2];
  __shared__ __align__(16) float pD[8][2][16][2];
  __shared__ u32 bcF;
  __shared__ float bcH;

  // ---- one-time setup ----
  {
    const float* wp = ws + OFF_WPACK/4;
    Wsm[tid] = wp[tid];
    if (tid < 132) Wsm[512 + tid] = wp[512 + tid];
  }
  if (tid < 64) yL[tid >> 1][tid & 1] = x0[wg*64 + tid];

  // resident W2/W3 fragments (A-operand: row n = wv*16 + nl, k = ks*32+g*8)
  const u16* w2th = (const u16*)((const char*)ws + OFF_W2TH);
  const u16* w2tl = (const u16*)((const char*)ws + OFF_W2TL);
  const u16* w3th = (const u16*)((const char*)ws + OFF_W3TH);
  const u16* w3tl = (const u16*)((const char*)ws + OFF_W3TL);
  short8 W2H[4], W2L[4], W3H[4], W3L[4];
  {
    const int nglob = wv*16 + nl;
#pragma unroll
    for (int ks = 0; ks < 4; ++ks) {
      int off = nglob*HID + ks*32 + g*8;
      W2H[ks] = *(const short8*)(w2th + off);
      W2L[ks] = *(const short8*)(w2tl + off);
      W3H[ks] = *(const short8*)(w3th + off);
      W3L[ks] = *(const short8*)(w3tl + off);
    }
  }
  // per-lane W4 slice: w4c[r][c] = W4[wv*16+g*4+r][c]
  float w4c[4][2];
#pragma unroll
  for (int r = 0; r < 4; ++r) {
    int n = wv*16 + g*4 + r;
    w4c[r][0] = W4g[n*2 + 0];
    w4c[r][1] = W4g[n*2 + 1];
  }
  __syncthreads();
  const f32x4 bv2 = *(const f32x4*)&Wsm[384 + wv*16 + g*4];
  const f32x4 bv3 = *(const f32x4*)&Wsm[512 + wv*16 + g*4];

  u64* esum = (u64*)((char*)ws + OFF_ESUM);
  u32* cnt  = (u32*)((char*)ws + OFF_CNT);

  float h = 0.5f * (t_arr[1] - t_arr[0]);
  float heff = h;

  // ---- phase A: inline stage combine (from pD) + L1 ----
  auto phaseA = [&](auto SC, int fromPD) {
    constexpr int S = decltype(SC)::v;
    const int m  = tid >> 4;        // 32 rows
    const int jc = tid & 15;        // 16 col-chunks of 8
    float ys0, ys1;
    const float y0 = yL[m][0], y1 = yL[m][1];
    if constexpr (S == 1) {
      ys0 = y0; ys1 = y1;
    } else {
      const int mt = m >> 4, ml = m & 15;
      float kp0, kp1;
      if (S == 2 && !fromPD) {
        kp0 = kS[0][m][0]; kp1 = kS[0][m][1];
      } else {
        kp0 = Wsm[640]; kp1 = Wsm[641];
#pragma unroll
        for (int w = 0; w < 8; ++w) {
          f32x2 p = *(const f32x2*)&pD[w][mt][ml][0];
          kp0 += p[0]; kp1 += p[1];
        }
        if (jc < 2) kS[S-2][m][jc] = jc ? kp1 : kp0;
      }
      if constexpr (S == 2) {
        ys0 = fmaf(heff, CA21*kp0, y0);
        ys1 = fmaf(heff, CA21*kp1, y1);
      } else if constexpr (S == 3) {
        f32x2 k1 = *(const f32x2*)&kS[0][m][0];
        ys0 = fmaf(heff, CA31*k1[0] + CA32*kp0, y0);
        ys1 = fmaf(heff, CA31*k1[1] + CA32*kp1, y1);
      } else if constexpr (S == 4) {
        f32x2 k1 = *(const f32x2*)&kS[0][m][0];
        f32x2 k2 = *(const f32x2*)&kS[1][m][0];
        ys0 = fmaf(heff, CA41*k1[0] + CA42*k2[0] + CA43*kp0, y0);
        ys1 = fmaf(heff, CA41*k1[1] + CA42*k2[1] + CA43*kp1, y1);
      } else if constexpr (S == 5) {
        f32x2 k1 = *(const f32x2*)&kS[0][m][0];
        f32x2 k2 = *(const f32x2*)&kS[1][m][0];
        f32x2 k3 = *(const f32x2*)&kS[2][m][0];
        ys0 = fmaf(heff, CA51*k1[0] + CA52*k2[0] + CA53*k3[0] + CA54*kp0, y0);
        ys1 = fmaf(heff, CA51*k1[1] + CA52*k2[1] + CA53*k3[1] + CA54*kp1, y1);
      } else if constexpr (S == 6) {
        f32x2 k1 = *(const f32x2*)&kS[0][m][0];
        f32x2 k2 = *(const f32x2*)&kS[1][m][0];
        f32x2 k3 = *(const f32x2*)&kS[2][m][0];
        f32x2 k4 = *(const f32x2*)&kS[3][m][0];
        ys0 = fmaf(heff, CA61*k1[0] + CA62*k2[0] + CA63*k3[0] + CA64*k4[0] + CA65*kp0, y0);
        ys1 = fmaf(heff, CA61*k1[1] + CA62*k2[1] + CA63*k3[1] + CA64*k4[1] + CA65*kp1, y1);
      } else {  // S == 7: y5
        f32x2 k1 = *(const f32x2*)&kS[0][m][0];
        f32x2 k3 = *(const f32x2*)&kS[2][m][0];
        f32x2 k4 = *(const f32x2*)&kS[3][m][0];
        f32x2 k5 = *(const f32x2*)&kS[4][m][0];
        ys0 = fmaf(heff, CB1*k1[0] + CB3*k3[0] + CB4*k4[0] + CB5*k5[0] + CB6*kp0, y0);
        ys1 = fmaf(heff, CB1*k1[1] + CB3*k3[1] + CB4*k4[1] + CB5*k5[1] + CB6*kp1, y1);
        if (jc < 2) y5L[m][jc] = jc ? ys1 : ys0;
      }
    }
    // L1: 8 cols per thread, single-bf16 pack
    const int j0 = jc * 8;
    f32x4 w0a = *(const f32x4*)&Wsm[j0],       w0b = *(const f32x4*)&Wsm[j0 + 4];
    f32x4 w1a = *(const f32x4*)&Wsm[128 + j0], w1b = *(const f32x4*)&Wsm[128 + j0 + 4];
    f32x4 ba  = *(const f32x4*)&Wsm[256 + j0], bb  = *(const f32x4*)&Wsm[256 + j0 + 4];
    float v0 = eluf(fmaf(ys1, w1a[0], fmaf(ys0, w0a[0], ba[0])));
    float v1 = eluf(fmaf(ys1, w1a[1], fmaf(ys0, w0a[1], ba[1])));
    float v2 = eluf(fmaf(ys1, w1a[2], fmaf(ys0, w0a[2], ba[2])));
    float v3 = eluf(fmaf(ys1, w1a[3], fmaf(ys0, w0a[3], ba[3])));
    float v4 = eluf(fmaf(ys1, w1b[0], fmaf(ys0, w0b[0], bb[0])));
    float v5 = eluf(fmaf(ys1, w1b[1], fmaf(ys0, w0b[1], bb[1])));
    float v6 = eluf(fmaf(ys1, w1b[2], fmaf(ys0, w0b[2], bb[2])));
    float v7 = eluf(fmaf(ys1, w1b[3], fmaf(ys0, w0b[3], bb[3])));
    u32x4 hp = {cvtpk(v0,v1), cvtpk(v2,v3), cvtpk(v4,v5), cvtpk(v6,v7)};
    *(u32x4*)&Ahi[0][m][j0] = hp;
  };

  // ---- L2: plane0 -> plane1 (2 MFMAs/tile: W-hi, W-lo) ----
  auto mmL2 = [&]() {
    f32x4 a0[2], a1[2];
    a0[0] = bv2; a0[1] = bv2; a1[0] = {0,0,0,0}; a1[1] = {0,0,0,0};
    __builtin_amdgcn_s_setprio(1);
#pragma unroll
    for (int ks = 0; ks < 4; ++ks)
#pragma unroll
      for (int mt = 0; mt < 2; ++mt) {
        short8 bh = *(const short8*)&Ahi[0][mt*16 + nl][ks*32 + g*8];
        a0[mt] = __builtin_amdgcn_mfma_f32_16x16x32_bf16(W2H[ks], bh, a0[mt], 0, 0, 0);
        a1[mt] = __builtin_amdgcn_mfma_f32_16x16x32_bf16(W2L[ks], bh, a1[mt], 0, 0, 0);
      }
    __builtin_amdgcn_s_setprio(0);
    const int n0 = wv*16 + g*4;
#pragma unroll
    for (int mt = 0; mt < 2; ++mt) {
      float v0 = eluf(a0[mt][0] + a1[mt][0]);
      float v1 = eluf(a0[mt][1] + a1[mt][1]);
      float v2 = eluf(a0[mt][2] + a1[mt][2]);
      float v3 = eluf(a0[mt][3] + a1[mt][3]);
      u32x2 hp = {cvtpk(v0, v1), cvtpk(v2, v3)};
      *(u32x2*)&Ahi[1][mt*16 + nl][n0] = hp;
    }
  };

  // ---- L3 + fused L4 dot -> pD ----
  auto mmL3 = [&]() {
    f32x4 a0[2], a1[2];
    a0[0] = bv3; a0[1] = bv3; a1[0] = {0,0,0,0}; a1[1] = {0,0,0,0};
    __builtin_amdgcn_s_setprio(1);
#pragma unroll
    for (int ks = 0; ks < 4; ++ks)
#pragma unroll
      for (int mt = 0; mt < 2; ++mt) {
        short8 bh = *(const short8*)&Ahi[1][mt*16 + nl][ks*32 + g*8];
        a0[mt] = __builtin_amdgcn_mfma_f32_16x16x32_bf16(W3H[ks], bh, a0[mt], 0, 0, 0);
        a1[mt] = __builtin_amdgcn_mfma_f32_16x16x32_bf16(W3L[ks], bh, a1[mt], 0, 0, 0);
      }
    __builtin_amdgcn_s_setprio(0);
#pragma unroll
    for (int mt = 0; mt < 2; ++mt) {
      float v0 = eluf(a0[mt][0] + a1[mt][0]);
      float v1 = eluf(a0[mt][1] + a1[mt][1]);
      float v2 = eluf(a0[mt][2] + a1[mt][2]);
      float v3 = eluf(a0[mt][3] + a1[mt][3]);
      float p0 = v0*w4c[0][0] + v1*w4c[1][0] + v2*w4c[2][0] + v3*w4c[3][0];
      float p1 = v0*w4c[0][1] + v1*w4c[1][1] + v2*w4c[2][1] + v3*w4c[3][1];
      p0 += __shfl_xor(p0, 16); p0 += __shfl_xor(p0, 32);
      p1 += __shfl_xor(p1, 16); p1 += __shfl_xor(p1, 32);
      if (lane < 16) {
        f32x2 pp = {p0, p1};
        *(f32x2*)&pD[wv][mt][lane][0] = pp;
      }
    }
  };

  // ---- main adaptive loop ----
  for (int iv = 0; iv < 7; ++iv) {
    const float t1 = t_arr[iv + 1];
    float tc = t_arr[iv];
    for (int s = 0; s < 8; ++s) {
      const int step = iv*8 + s;
      float rem = t1 - tc;
      if (rem <= 1e-9f) break;          // uniform across all WGs
      heff = fminf(h, rem);

      if (iv == 0 && s == 0) {          // fresh k1 eval
        phaseA(IC<1>{}, 0); __syncthreads();
        mmL2(); __syncthreads();
        mmL3(); __syncthreads();
        phaseA(IC<2>{}, 1);
      } else {
        phaseA(IC<2>{}, 0);             // FSAL: k1 = kS[0]
      }
      __syncthreads(); mmL2(); __syncthreads(); mmL3(); __syncthreads();
      phaseA(IC<3>{}, 1); __syncthreads(); mmL2(); __syncthreads(); mmL3(); __syncthreads();
      phaseA(IC<4>{}, 1); __syncthreads(); mmL2(); __syncthreads(); mmL3(); __syncthreads();
      phaseA(IC<5>{}, 1); __syncthreads(); mmL2(); __syncthreads(); mmL3(); __syncthreads();
      phaseA(IC<6>{}, 1); __syncthreads(); mmL2(); __syncthreads(); mmL3(); __syncthreads();
      phaseA(IC<7>{}, 1); __syncthreads(); mmL2(); __syncthreads(); mmL3(); __syncthreads();
      // pD now holds k7 partials

      // ---- error partial (wave 0) + deterministic fixed-point publish ----
      if (wv == 0) {
        int m = lane >> 1, c = lane & 1;
        int emt = m >> 4, eml = m & 15;
        float kp = Wsm[640 + c];
#pragma unroll
        for (int w = 0; w < 8; ++w) kp += pD[w][emt][eml][c];
        kS[6][m][c] = kp;
        float e = heff * (CE1*kS[0][m][c] + CE3*kS[2][m][c] + CE4*kS[3][m][c]
                        + CE5*kS[4][m][c] + CE6*kS[5][m][c] + CE7*kp);
        float tol = 1e-4f + 1e-3f * fmaxf(fabsf(yL[m][c]), fabsf(y5L[m][c]));
        float rr = e / tol;
        float es = rr * rr;
#pragma unroll
        for (int mk = 1; mk < 64; mk <<= 1) es += __shfl_xor(es, mk);
        if (lane == 0) {
          if (!(es < 1e8f)) es = 1e8f;          // clamp; also catches NaN
          u64 q = (u64)(es * 1048576.0f);       // x 2^20 fixed point
          __hip_atomic_fetch_add(&esum[step], q, __ATOMIC_RELAXED, __HIP_MEMORY_SCOPE_AGENT);
          __hip_atomic_fetch_add(&cnt[step], 1u, __ATOMIC_RELEASE, __HIP_MEMORY_SCOPE_AGENT);
        }
      }
      // ---- every WG: poll + local identical decision ----
      if (tid == 0) {
        while (__hip_atomic_load(&cnt[step], __ATOMIC_ACQUIRE, __HIP_MEMORY_SCOPE_AGENT) < (u32)NWG)
          __builtin_amdgcn_s_sleep(1);
        u64 q = __hip_atomic_load(&esum[step], __ATOMIC_RELAXED, __HIP_MEMORY_SCOPE_AGENT);
        float sum = (float)q * (1.0f/1048576.0f);
        float err_norm = sqrtf(sum * (1.0f/16384.f));
        bool acc = (err_norm <= 1.0f);
        float factor = fminf(10.f, fmaxf(0.2f, 0.9f * powf(fmaxf(err_norm, 1e-10f), -0.2f)));
        bcF = acc ? 1u : 0u;
        bcH = heff * factor;
      }
      __syncthreads();
      {
        bool acc = bcF != 0u;
        if (acc) {
          if (tid < 64) { int m = tid >> 1, c = tid & 1;
            yL[m][c] = y5L[m][c];
            kS[0][m][c] = kS[6][m][c];   // FSAL: k1 <- k7
          }
          tc += heff;
        }
        h = bcH;
      }
      __syncthreads();
    }
    if (tid < 64)
      out[(size_t)(iv + 1) * 16384 + wg*64 + tid] = yL[tid >> 1][tid & 1];
  }
}

extern "C" void kernel_launch(void* const* d_in, const int* in_sizes, int n_in,
                              void* d_out, int out_size, void* d_ws, size_t ws_size,
                              hipStream_t stream)
{
  const float* x0 = (const float*)d_in[0];
  const float* t  = (const float*)d_in[1];
  const float* W1 = (const float*)d_in[2];
  const float* b1 = (const float*)d_in[3];
  const float* W2 = (const float*)d_in[4];
  const float* b2 = (const float*)d_in[5];
  const float* W3 = (const float*)d_in[6];
  const float* b3 = (const float*)d_in[7];
  const float* W4 = (const float*)d_in[8];
  const float* b4 = (const float*)d_in[9];
  float* out = (float*)d_out;
  float* ws  = (float*)d_ws;

  prologue<<<64, 256, 0, stream>>>(x0, t, W1, b1, W2, b2, W3, b3, W4, b4, ws, out);
  solver<<<NWG, NTHR, 0, stream>>>(x0, t, W4, ws, out);
}